// Round 5
// baseline (2311.305 us; speedup 1.0000x reference)
//
#include <hip/hip_runtime.h>
#include <hip/hip_bf16.h>

typedef unsigned short u16;
typedef __attribute__((ext_vector_type(8))) short short8;
typedef __attribute__((ext_vector_type(4))) float floatx4;

#define FLAG_GELU   1
#define FLAG_ACC    2
#define FLAG_NN     4
#define FLAG_CF32   8
#define FLAG_ATOMIC 16

__device__ __forceinline__ float bf2f(u16 u){
  union { unsigned u; float f; } c; c.u = ((unsigned)u)<<16; return c.f;
}
__device__ __forceinline__ u16 f2bf(float f){
  union { float f; unsigned u; } c; c.f = f;
  unsigned r = (c.u + 0x7fffu + ((c.u>>16)&1u))>>16;
  return (u16)r;
}
__device__ __forceinline__ float rdin(const void* base, long long idx, int flagv){
  return flagv ? ((const float*)base)[idx] : bf2f(((const u16*)base)[idx]);
}
// tanh-approx GELU via fast exp: tanh(u) = 1 - 2/(e^{2u}+1); saturates correctly.
__device__ __forceinline__ float fast_gelu(float x){
  float u = 0.7978845608028654f*(x + 0.044715f*x*x*x);
  float e = __expf(2.f*u);
  float t = 1.f - 2.f/(e+1.f);
  return 0.5f*x*(1.f+t);
}

// ---------------- input dtype probe ----------------
__global__ void detect_kernel(const void* tok, int* flag){
  __shared__ int cnt;
  if(threadIdx.x==0) cnt=0;
  __syncthreads();
  float v = fabsf(bf2f(((const u16*)tok)[threadIdx.x]));
  int bad = (v < 1e3f) ? 0 : 1;
  atomicAdd(&cnt, bad);
  __syncthreads();
  if(threadIdx.x==0) *flag = (cnt>0) ? 1 : 0;
}

// ---------------- fused dual-dtype convert + transpose: src[K][N] -> dst[N][K] bf16 ----------------
__global__ void cvtT_kernel(const void* src, long long off0, long long zstride, u16* __restrict__ dst,
    long long dzstride, int K, int N, const int* flag){
  __shared__ float tl[32][33];
  int fl = *flag;
  int k0 = blockIdx.x*32, n0 = blockIdx.y*32;
  long long base = off0 + (long long)blockIdx.z*zstride;
  for(int i=threadIdx.y;i<32;i+=8){
    long long idx = base + (long long)(k0+i)*N + n0 + threadIdx.x;
    tl[i][threadIdx.x] = fl ? ((const float*)src)[idx] : bf2f(((const u16*)src)[idx]);
  }
  __syncthreads();
  u16* dz = dst + (long long)blockIdx.z*dzstride;
  for(int i=threadIdx.y;i<32;i+=8)
    dz[(long long)(n0+i)*K + k0 + threadIdx.x] = f2bf(tl[threadIdx.x][i]);
}

// ---------------- bf16 ws->ws transpose, batched ----------------
__global__ void transposeB_kernel(const u16* __restrict__ in, u16* __restrict__ out,
    long long izs0, long long izs1, int zd, long long ozstride, int ldin, int ldout){
  __shared__ u16 tl[32][33];
  int z = blockIdx.z; int z0 = z/zd, z1 = z - z0*zd;
  const u16* ip = in + z0*izs0 + z1*izs1;
  u16* op = out + (long long)z*ozstride;
  int r0 = blockIdx.x*32, c0 = blockIdx.y*32;
  for(int i=threadIdx.y;i<32;i+=8)
    tl[i][threadIdx.x] = ip[(long long)(r0+i)*ldin + c0 + threadIdx.x];
  __syncthreads();
  for(int i=threadIdx.y;i<32;i+=8)
    op[(long long)(c0+i)*ldout + r0 + threadIdx.x] = tl[threadIdx.x][i];
}

__global__ __launch_bounds__(256) void zerof_kernel(float* p, int n){
  int i = blockIdx.x*256 + threadIdx.x;
  if(i<n) p[i]=0.f;
}

// ---------------- 64x64 batched GEMM (attention pre-stage shapes) ----------------
struct GemmP {
  const u16* A; const u16* B; float* Cf; u16* Ch;
  const void* bias; int biasOff; const int* dflag;
  int K, lda, ldb, ldc;
  long long sA0,sA1,sA2,sB0,sB1,sB2,sC0,sC1,sC2;
  int d0,d1; float alpha; int flags; int ksplit;
};

__global__ __launch_bounds__(256) void gemm_kernel(GemmP p){
  __shared__ __align__(16) u16 As[64][40];
  __shared__ __align__(16) u16 Bs[64][40];
  int z = blockIdx.z;
  int i0 = z / p.d0; int rem = z - i0*p.d0; int i1 = rem / p.d1; int i2 = rem - i1*p.d1;
  const u16* A  = p.A + i0*p.sA0 + i1*p.sA1 + i2*p.sA2;
  const u16* Bp = p.B + i0*p.sB0 + i1*p.sB1 + i2*p.sB2;
  long long cb = i0*p.sC0 + i1*p.sC1 + i2*p.sC2;
  int kbeg = 0, kend = p.K;
  if(p.ksplit){ kbeg = i2*p.ksplit; kend = kbeg + p.ksplit; }
  int m0 = blockIdx.x*64, n0 = blockIdx.y*64;
  int t = threadIdx.x, lane = t&63, wave = t>>6;
  int wm = (wave>>1)*32, wn = (wave&1)*32;
  int quad = lane>>4, l16 = lane&15;
  floatx4 zero4 = {0.f,0.f,0.f,0.f};
  floatx4 acc00=zero4, acc01=zero4, acc10=zero4, acc11=zero4;
  int sr = t>>2, sc = (t&3)*8;
  int bkr = t>>3, bnc = (t&7)*8;
  bool nn = (p.flags & FLAG_NN);
  for(int k0=kbeg;k0<kend;k0+=32){
    uint4 av = *(const uint4*)(A + (long long)(m0+sr)*p.lda + (k0+sc));
    uint4 bv;
    if(nn) bv = *(const uint4*)(Bp + (long long)(k0+bkr)*p.ldb + (n0+bnc));
    else   bv = *(const uint4*)(Bp + (long long)(n0+sr)*p.ldb + (k0+sc));
    *(uint4*)&As[sr][sc] = av;
    if(nn){
      u16 tmp[8]; *(uint4*)tmp = bv;
      #pragma unroll
      for(int j=0;j<8;j++) Bs[bnc+j][bkr] = tmp[j];
    } else {
      *(uint4*)&Bs[sr][sc] = bv;
    }
    __syncthreads();
    short8 a0 = *(const short8*)&As[wm+l16][quad*8];
    short8 a1 = *(const short8*)&As[wm+16+l16][quad*8];
    short8 b0 = *(const short8*)&Bs[wn+l16][quad*8];
    short8 b1 = *(const short8*)&Bs[wn+16+l16][quad*8];
    acc00 = __builtin_amdgcn_mfma_f32_16x16x32_bf16(a0,b0,acc00,0,0,0);
    acc01 = __builtin_amdgcn_mfma_f32_16x16x32_bf16(a0,b1,acc01,0,0,0);
    acc10 = __builtin_amdgcn_mfma_f32_16x16x32_bf16(a1,b0,acc10,0,0,0);
    acc11 = __builtin_amdgcn_mfma_f32_16x16x32_bf16(a1,b1,acc11,0,0,0);
    __syncthreads();
  }
  int flagv = p.bias ? *p.dflag : 0;
  #pragma unroll
  for(int mi=0;mi<2;mi++){
    #pragma unroll
    for(int ni=0;ni<2;ni++){
      floatx4 a = (mi==0)?((ni==0)?acc00:acc01):((ni==0)?acc10:acc11);
      int cg = n0 + wn + ni*16 + l16;
      float bv_ = p.bias ? rdin(p.bias, (long long)p.biasOff + cg, flagv) : 0.f;
      #pragma unroll
      for(int e=0;e<4;e++){
        int rg = m0 + wm + mi*16 + quad*4 + e;
        float v = a[e]*p.alpha + bv_;
        if(p.flags & FLAG_GELU) v = fast_gelu(v);
        long long ci = cb + (long long)rg*p.ldc + cg;
        if(p.flags & FLAG_ATOMIC){
          atomicAdd(&p.Cf[ci], v);
        } else if(p.flags & FLAG_CF32){
          float o2 = v; if(p.flags&FLAG_ACC) o2 += p.Cf[ci];
          p.Cf[ci] = o2;
        } else {
          float o2 = v; if(p.flags&FLAG_ACC) o2 += bf2f(p.Ch[ci]);
          p.Ch[ci] = f2bf(o2);
        }
      }
    }
  }
}

// ---------------- big-GEMM params ----------------
struct Gemm128P {
  const u16* A; const u16* B; float* Cf; u16* Ch;
  const void* bias; int biasOff; const int* dflag;
  int K, lda, ldb, ldc; float alpha; int flags;
};

// ---------------- 128x256 GEMM, BK=64, TRIPLE-buffered counted-vmcnt pipeline ----------------
// 512 threads = 8 waves (2M x 4N), per-wave 64x64 out. Loads issued 2 K-tiles
// ahead (6 gload_lds/wave/tile); steady-state wait = vmcnt(12) (2 tiles in
// flight), raw s_barrier (NO full drain), lgkmcnt(0)+barrier before buffer
// reuse. T2 source-swizzle kept (bank-conflict-free, proven r3). sched_barrier
// fences pin the ds_read/MFMA region between barriers (rule #18).
__global__ __launch_bounds__(512) void gemm3b_kernel(Gemm128P p){
  constexpr int TILE_A = 8192;    // 128x64 u16
  constexpr int TILE_B = 16384;   // 256x64 u16
  constexpr int TILE   = TILE_A + TILE_B;   // 24576 u16 per buffer
  __shared__ __align__(16) u16 lds[3*TILE]; // 147456 B
  int m0 = blockIdx.x*128, n0 = blockIdx.y*256;
  int t = threadIdx.x, lane = t&63, wave = t>>6;
  int quad = lane>>4, l16 = lane&15;
  int wr = wave>>2, wc = wave&3;
  int rowA = t>>3;
  int colk = ((t&7) ^ (rowA&7))*8;        // inverse-swizzled source column
  const u16* Asrc0 = p.A + (long long)(m0 + rowA)*p.lda + colk;
  const u16* Asrc1 = p.A + (long long)(m0 + 64 + rowA)*p.lda + colk;
  const u16* Bsrc[4];
  #pragma unroll
  for(int q=0;q<4;q++) Bsrc[q] = p.B + (long long)(n0 + q*64 + rowA)*p.ldb + colk;
  int nk = p.K >> 6;
  floatx4 acc[4][4] = {};

  auto stage = [&](int buf, int k0){
    u16* base = lds + buf*TILE;
    __builtin_amdgcn_global_load_lds(
      (const __attribute__((address_space(1))) unsigned int*)(Asrc0 + k0),
      (__attribute__((address_space(3))) unsigned int*)(base + wave*512), 16, 0, 0);
    __builtin_amdgcn_global_load_lds(
      (const __attribute__((address_space(1))) unsigned int*)(Asrc1 + k0),
      (__attribute__((address_space(3))) unsigned int*)(base + 4096 + wave*512), 16, 0, 0);
    #pragma unroll
    for(int q=0;q<4;q++)
      __builtin_amdgcn_global_load_lds(
        (const __attribute__((address_space(1))) unsigned int*)(Bsrc[q] + k0),
        (__attribute__((address_space(3))) unsigned int*)(base + TILE_A + q*4096 + wave*512), 16, 0, 0);
  };

  stage(0, 0);
  if(nk>1) stage(1, 64);
  int sw = l16&7;
  for(int kt=0; kt<nk; ++kt){
    if(kt+2<nk){
      stage((kt+2)%3, (kt+2)*64);
      asm volatile("s_waitcnt vmcnt(12)" ::: "memory");   // tile kt resident; kt+1,kt+2 in flight
    } else if(kt+1<nk){
      asm volatile("s_waitcnt vmcnt(6)" ::: "memory");
    } else {
      asm volatile("s_waitcnt vmcnt(0)" ::: "memory");
    }
    __builtin_amdgcn_s_barrier();                          // all waves' tile-kt loads done
    __builtin_amdgcn_sched_barrier(0);
    const u16* Ab = lds + (kt%3)*TILE;
    const u16* Bb = Ab + TILE_A;
    #pragma unroll
    for(int ks=0; ks<2; ks++){
      short8 a[4], b[4];
      #pragma unroll
      for(int i=0;i<4;i++)
        a[i] = *(const short8*)&Ab[(wr*64 + i*16 + l16)*64 + ((((ks<<2)|quad) ^ sw)<<3)];
      #pragma unroll
      for(int j=0;j<4;j++)
        b[j] = *(const short8*)&Bb[(wc*64 + j*16 + l16)*64 + ((((ks<<2)|quad) ^ sw)<<3)];
      #pragma unroll
      for(int i=0;i<4;i++)
        #pragma unroll
        for(int j=0;j<4;j++)
          acc[i][j] = __builtin_amdgcn_mfma_f32_16x16x32_bf16(a[i], b[j], acc[i][j],0,0,0);
    }
    __builtin_amdgcn_sched_barrier(0);
    asm volatile("s_waitcnt lgkmcnt(0)" ::: "memory");     // my ds_reads retired
    __builtin_amdgcn_s_barrier();                          // buf[kt%3] safe to overwrite next iter
  }

  int flagv = p.bias ? *p.dflag : 0;
  if(!(p.flags & FLAG_CF32)){
    // bf16 out: transpose tile through LDS (wave-private), store 16B lines.
    u16* Ct = lds + wave*(64*68);
    #pragma unroll
    for(int j=0;j<4;j++){
      int cg = n0 + wc*64 + j*16 + l16;
      float bv_ = p.bias ? rdin(p.bias, (long long)p.biasOff + cg, flagv) : 0.f;
      #pragma unroll
      for(int i=0;i<4;i++){
        #pragma unroll
        for(int e=0;e<4;e++){
          float v = acc[i][j][e]*p.alpha + bv_;
          if(p.flags & FLAG_GELU) v = fast_gelu(v);
          Ct[(i*16 + quad*4 + e)*68 + j*16 + l16] = f2bf(v);
        }
      }
    }
    int rsub = lane>>3, csub = (lane&7)*8;
    #pragma unroll
    for(int rr=0; rr<8; rr++){
      int row = rr*8 + rsub;
      uint4 v = *(const uint4*)&Ct[row*68 + csub];
      *(uint4*)(p.Ch + (long long)(m0 + wr*64 + row)*p.ldc + (n0 + wc*64 + csub)) = v;
    }
  } else {
    #pragma unroll
    for(int j=0;j<4;j++){
      int cg = n0 + wc*64 + j*16 + l16;
      float bv_ = p.bias ? rdin(p.bias, (long long)p.biasOff + cg, flagv) : 0.f;
      #pragma unroll
      for(int i=0;i<4;i++){
        #pragma unroll
        for(int e=0;e<4;e++){
          int rg = m0 + wr*64 + i*16 + quad*4 + e;
          float v = acc[i][j][e]*p.alpha + bv_;
          if(p.flags & FLAG_GELU) v = fast_gelu(v);
          long long ci = (long long)rg*p.ldc + cg;
          float o2 = v; if(p.flags&FLAG_ACC) o2 += p.Cf[ci];
          p.Cf[ci] = o2;
        }
      }
    }
  }
}

// ---------------- fused window attention (occupancy-optimized) ----------------
struct AttnP {
  const u16* q;    // [B][4096][512] (pre-scaled)
  const u16* k;    // LN'd kv base [B][4096][1024], head offset h*64
  const u16* gk;   // [bh][256][64] (LN'd)
  const u16* vT;   // [bh][64][4096] (LN'd local v, transposed)
  const u16* gvT;  // [bh][64][256]  (LN'd global v, transposed)
  u16* o;          // [B][4096][512]
};

__global__ __launch_bounds__(256) void attn_kernel(AttnP p){
  __shared__ __align__(16) u16 S[32*392];   // 32 rows x 392 stride
  __shared__ float ssum[32];
  const int SST = 392;
  int qb = blockIdx.x;          // 0..127 : 32-row q tile
  int bh = blockIdx.y;
  int b = bh>>3, hh = bh&7;
  int w = qb>>2;                // 128-row window this tile belongs to
  int t = threadIdx.x, lane = t&63, wave = t>>6;
  int quad = lane>>4, l16 = lane&15;
  int mbase = qb*32;
  short8 aq[2][2];
  #pragma unroll
  for(int mt=0;mt<2;mt++)
    #pragma unroll
    for(int kc=0;kc<2;kc++)
      aq[mt][kc] = *(const short8*)(p.q + ((long long)b*4096 + mbase + mt*16 + l16)*512 + hh*64 + kc*32 + quad*8);
  #pragma unroll
  for(int i=0;i<6;i++){
    int ct = wave*6 + i;
    short8 bf0, bf1;
    if(ct<8){
      const u16* kr = p.k + ((long long)b*4096 + w*128 + ct*16 + l16)*1024 + hh*64;
      bf0 = *(const short8*)(kr + quad*8);
      bf1 = *(const short8*)(kr + 32 + quad*8);
    } else {
      const u16* gr = p.gk + ((long long)bh*256 + (ct-8)*16 + l16)*64;
      bf0 = *(const short8*)(gr + quad*8);
      bf1 = *(const short8*)(gr + 32 + quad*8);
    }
    #pragma unroll
    for(int mt=0;mt<2;mt++){
      floatx4 acc = {0.f,0.f,0.f,0.f};
      acc = __builtin_amdgcn_mfma_f32_16x16x32_bf16(aq[mt][0], bf0, acc,0,0,0);
      acc = __builtin_amdgcn_mfma_f32_16x16x32_bf16(aq[mt][1], bf1, acc,0,0,0);
      #pragma unroll
      for(int e=0;e<4;e++)
        S[(mt*16 + quad*4 + e)*SST + ct*16 + l16] = f2bf(acc[e]);
    }
  }
  __syncthreads();
  {
    int r = t>>3, seg = t&7;
    u16* Srow = S + r*SST + seg*48;
    u16 buf[48];
    #pragma unroll
    for(int it=0; it<6; it++)
      *(uint4*)(buf + it*8) = *(const uint4*)(Srow + it*8);
    float mmax = -3.4e38f;
    #pragma unroll
    for(int j=0;j<48;j++) mmax = fmaxf(mmax, bf2f(buf[j]));
    mmax = fmaxf(mmax, __shfl_xor(mmax, 1));
    mmax = fmaxf(mmax, __shfl_xor(mmax, 2));
    mmax = fmaxf(mmax, __shfl_xor(mmax, 4));
    float s = 0.f;
    #pragma unroll
    for(int j=0;j<48;j++){ float e_ = __expf(bf2f(buf[j]) - mmax); s += e_; buf[j] = f2bf(e_); }
    #pragma unroll
    for(int it=0; it<6; it++)
      *(uint4*)(Srow + it*8) = *(const uint4*)(buf + it*8);
    s += __shfl_xor(s, 1);
    s += __shfl_xor(s, 2);
    s += __shfl_xor(s, 4);
    if(seg==0) ssum[r] = 1.f/s;
  }
  __syncthreads();
  int dt = wave;
  floatx4 oacc[2] = {};
  for(int kc=0; kc<12; kc++){
    short8 ap0 = *(const short8*)(S + (l16)*SST + kc*32 + quad*8);
    short8 ap1 = *(const short8*)(S + (16 + l16)*SST + kc*32 + quad*8);
    short8 bv;
    if(kc<4)
      bv = *(const short8*)(p.vT + (long long)bh*262144 + (dt*16+l16)*4096 + w*128 + kc*32 + quad*8);
    else
      bv = *(const short8*)(p.gvT + (long long)bh*16384 + (dt*16+l16)*256 + (kc-4)*32 + quad*8);
    oacc[0] = __builtin_amdgcn_mfma_f32_16x16x32_bf16(ap0, bv, oacc[0],0,0,0);
    oacc[1] = __builtin_amdgcn_mfma_f32_16x16x32_bf16(ap1, bv, oacc[1],0,0,0);
  }
  #pragma unroll
  for(int mt=0;mt<2;mt++){
    #pragma unroll
    for(int e=0;e<4;e++){
      int row = mt*16 + quad*4 + e;
      float inv = ssum[row];
      p.o[((long long)b*4096 + mbase + row)*512 + hh*64 + dt*16 + l16] = f2bf(oacc[mt][e]*inv);
    }
  }
}

// ---------------- embed ----------------
__global__ __launch_bounds__(256) void embed_kernel(const int* __restrict__ x, const void* tok,
    const void* pos, float* __restrict__ h, const int* flag){
  int i = blockIdx.x*256 + threadIdx.x;
  int flagv = *flag;
  int d = i & 511;
  int n = (i>>9) & 4095;
  int bn = i>>9;
  int tid2 = x[bn];
  h[i] = rdin(tok, (long long)tid2*512 + d, flagv) + rdin(pos, (long long)n*512 + d, flagv);
}

// ---------------- LN over 512 (fp32 in, bf16 out) ----------------
__global__ __launch_bounds__(256) void ln512_kernel(const float* __restrict__ h,
    const void* g, const void* b, int goff, u16* __restrict__ y, const int* flag){
  int row = blockIdx.x;
  int flagv = *flag;
  const float* hr = h + (size_t)row*512;
  int t = threadIdx.x;
  float x0 = hr[t], x1 = hr[t+256];
  float s1 = x0+x1, s2 = x0*x0+x1*x1;
  for(int o=32;o>0;o>>=1){ s1 += __shfl_down(s1,o,64); s2 += __shfl_down(s2,o,64); }
  __shared__ float sh1[4], sh2[4];
  int wv=t>>6, ln=t&63;
  if(ln==0){ sh1[wv]=s1; sh2[wv]=s2; }
  __syncthreads();
  float st = sh1[0]+sh1[1]+sh1[2]+sh1[3];
  float qt = sh2[0]+sh2[1]+sh2[2]+sh2[3];
  float mu = st*(1.f/512.f);
  float var = qt*(1.f/512.f) - mu*mu;
  float inv = rsqrtf(var+1e-5f);
  u16* yr = y + (size_t)row*512;
  yr[t]     = f2bf((x0-mu)*inv*rdin(g,goff+t,flagv)     + rdin(b,goff+t,flagv));
  yr[t+256] = f2bf((x1-mu)*inv*rdin(g,goff+t+256,flagv) + rdin(b,goff+t+256,flagv));
}

// ---------------- LN over 64; optional fp32 input; strided ----------------
__global__ __launch_bounds__(256) void ln64_kernel(const u16* __restrict__ in, const float* __restrict__ inF,
    u16* __restrict__ out, const void* g, const void* b, int goff,
    long long s0, long long s1v, long long s2v, int d0, int d1, const int* flag){
  int r = blockIdx.x*4 + (threadIdx.x>>6);
  int ln = threadIdx.x&63;
  int flagv = *flag;
  int i0 = r/d0; int rem = r - i0*d0; int i1 = rem/d1; int i2 = rem - i1*d1;
  long long off = i0*s0 + i1*s1v + i2*s2v;
  float x = inF ? inF[off+ln] : bf2f(in[off + ln]);
  float s = x, sq = x*x;
  for(int o=32;o>0;o>>=1){ s += __shfl_down(s,o,64); sq += __shfl_down(sq,o,64); }
  s = __shfl(s,0,64); sq = __shfl(sq,0,64);
  float mu = s*(1.f/64.f), var = sq*(1.f/64.f)-mu*mu;
  float inv = rsqrtf(var+1e-5f);
  out[off + ln] = f2bf((x-mu)*inv*rdin(g,goff+ln,flagv) + rdin(b,goff+ln,flagv));
}

// ---------------- softmax over 4096 (bf16, in place) ----------------
__global__ __launch_bounds__(256) void softmax4096_kernel(u16* __restrict__ p){
  u16* pr = p + (size_t)blockIdx.x*4096;
  int t = threadIdx.x;
  u16 tmp[16];
  *(uint4*)tmp     = *(const uint4*)(pr + t*16);
  *(uint4*)(tmp+8) = *(const uint4*)(pr + t*16 + 8);
  float xs[16]; float m=-3.4e38f;
  #pragma unroll
  for(int i=0;i<16;i++){ xs[i]=bf2f(tmp[i]); m=fmaxf(m,xs[i]); }
  for(int o=32;o>0;o>>=1) m = fmaxf(m, __shfl_down(m,o,64));
  __shared__ float sm[4]; __shared__ float sv[4];
  int wv=t>>6, ln=t&63;
  if(ln==0) sm[wv]=m;
  __syncthreads();
  m = fmaxf(fmaxf(sm[0],sm[1]),fmaxf(sm[2],sm[3]));
  float s=0;
  #pragma unroll
  for(int i=0;i<16;i++){ xs[i]=__expf(xs[i]-m); s+=xs[i]; }
  for(int o=32;o>0;o>>=1) s += __shfl_down(s,o,64);
  if(ln==0) sv[wv]=s;
  __syncthreads();
  s = sv[0]+sv[1]+sv[2]+sv[3];
  float inv = 1.f/s;
  #pragma unroll
  for(int i=0;i<16;i++) tmp[i]=f2bf(xs[i]*inv);
  *(uint4*)(pr + t*16)     = *(uint4*)tmp;
  *(uint4*)(pr + t*16 + 8) = *(uint4*)(tmp+8);
}

// ---------------- head ----------------
__global__ void zero40_kernel(float* p){ if(threadIdx.x<40) p[threadIdx.x]=0.f; }

// out[b][c] = sum_j logits[b][j] * W[j][c].  Grid = 1024 blocks, each owns 2048
// CONSECUTIVE W rows and all 4 batches (W read exactly once, coalesced).
__global__ __launch_bounds__(256) void head_kernel(const float* __restrict__ logits,
    const void* wfin, float* __restrict__ part, const int* flag){
  __shared__ __align__(16) u16 Wl[20480];   // 2048 rows x 10 bf16
  __shared__ float redl[4][40];
  int flagv = *flag;
  int t = threadIdx.x;
  long long rbase = (long long)blockIdx.x*2048;
  float acc[4][10];
  #pragma unroll
  for(int b4=0;b4<4;b4++)
    #pragma unroll
    for(int c=0;c<10;c++) acc[b4][c]=0.f;

  if(!flagv){
    const uint4* src = (const uint4*)((const u16*)wfin + rbase*10);
    uint4* dst = (uint4*)Wl;
    #pragma unroll
    for(int i=0;i<10;i++) dst[t + i*256] = src[t + i*256];
    __syncthreads();
    const unsigned* Wd = (const unsigned*)Wl;
    #pragma unroll
    for(int i=0;i<8;i++){
      int r = t + i*256;
      float l0 = logits[rbase + r];
      float l1 = logits[2097152 + rbase + r];
      float l2 = logits[4194304 + rbase + r];
      float l3 = logits[6291456 + rbase + r];
      #pragma unroll
      for(int k2=0;k2<5;k2++){
        unsigned d = Wd[r*5 + k2];
        float w0 = bf2f((u16)(d & 0xffffu));
        float w1 = bf2f((u16)(d >> 16));
        acc[0][2*k2]   += l0*w0; acc[0][2*k2+1] += l0*w1;
        acc[1][2*k2]   += l1*w0; acc[1][2*k2+1] += l1*w1;
        acc[2][2*k2]   += l2*w0; acc[2][2*k2+1] += l2*w1;
        acc[3][2*k2]   += l3*w0; acc[3][2*k2+1] += l3*w1;
      }
    }
  } else {
    #pragma unroll
    for(int i=0;i<8;i++){
      int r = t + i*256;
      float l0 = logits[rbase + r];
      float l1 = logits[2097152 + rbase + r];
      float l2 = logits[4194304 + rbase + r];
      float l3 = logits[6291456 + rbase + r];
      const float* wr = (const float*)wfin + (rbase + r)*10;
      #pragma unroll
      for(int c=0;c<10;c++){
        float w = wr[c];
        acc[0][c] += l0*w; acc[1][c] += l1*w; acc[2][c] += l2*w; acc[3][c] += l3*w;
      }
    }
  }
  int wv = t>>6, ln = t&63;
  #pragma unroll
  for(int b4=0;b4<4;b4++)
    #pragma unroll
    for(int c=0;c<10;c++){
      float v = acc[b4][c];
      for(int o=32;o>0;o>>=1) v += __shfl_down(v,o,64);
      if(ln==0) redl[wv][b4*10+c] = v;
    }
  __syncthreads();
  if(t<40) atomicAdd(&part[t], redl[0][t]+redl[1][t]+redl[2][t]+redl[3][t]);
}

__global__ void fin_kernel(const float* __restrict__ part, const void* bfin, void* out, const int* flag){
  int i=threadIdx.x;
  int flagv = *flag;
  if(i<40){
    float r = part[i] + rdin(bfin, i%10, flagv);
    if(flagv) ((float*)out)[i] = r;
    else      ((u16*)out)[i]   = f2bf(r);
  }
}

// ---------------- workspace layout (bytes) — total ~209.8 MB ----------------
static const size_t OFF_H    = 0;
static const size_t OFF_Y    = 33554432;
static const size_t OFF_GKF  = 33554432;
static const size_t OFF_GVF  = 35651584;
static const size_t OFF_Q    = 50331648;
static const size_t OFF_KV   = 67108864;
static const size_t OFF_GK   = 100663296;
static const size_t OFF_GV   = 101711872;
static const size_t OFF_BIG  = 102760448;
static const size_t OFF_KT   = 169869312;   // gvT
static const size_t OFF_VT   = 186646528;   // LN'd v^T
static const size_t OFF_WTP  = 203423744;
static const size_t OFF_WQT  = 203554816;
static const size_t OFF_WKVT = 204079104;
static const size_t OFF_WOT  = 205127680;
static const size_t OFF_W1T  = 205651968;
static const size_t OFF_W2T  = 207749120;
static const size_t OFF_PART = 209846272;
static const size_t OFF_FLAG = 209846528;
static const size_t WS_NEED  = 209846784;

static inline GemmP mkg(const void*A,const void*B,void*C,const void*bias,int biasOff,const int* dflag,
  int K,int lda,int ldb,int ldc,
  long long a0,long long a1,long long a2,long long b0,long long b1,long long b2,
  long long c0,long long c1,long long c2,int d0,int d1,float alpha,int flags,int ksplit){
  GemmP p; p.A=(const u16*)A; p.B=(const u16*)B;
  p.Cf=(float*)C; p.Ch=(u16*)C; p.bias=bias; p.biasOff=biasOff; p.dflag=dflag;
  p.K=K;p.lda=lda;p.ldb=ldb;p.ldc=ldc;
  p.sA0=a0;p.sA1=a1;p.sA2=a2;p.sB0=b0;p.sB1=b1;p.sB2=b2;p.sC0=c0;p.sC1=c1;p.sC2=c2;
  p.d0=d0;p.d1=d1;p.alpha=alpha;p.flags=flags;p.ksplit=ksplit; return p;
}
static inline Gemm128P mk128(const void*A,const void*B,void*C,const void*bias,int biasOff,const int* dflag,
  int K,int lda,int ldb,int ldc,float alpha,int flags){
  Gemm128P p; p.A=(const u16*)A; p.B=(const u16*)B;
  p.Cf=(float*)C; p.Ch=(u16*)C; p.bias=bias; p.biasOff=biasOff; p.dflag=dflag;
  p.K=K;p.lda=lda;p.ldb=ldb;p.ldc=ldc;p.alpha=alpha;p.flags=flags; return p;
}

extern "C" void kernel_launch(void* const* d_in, const int* in_sizes, int n_in,
                              void* d_out, int out_size, void* d_ws, size_t ws_size,
                              hipStream_t stream){
  (void)in_sizes;(void)n_in;(void)out_size;
  if(ws_size < WS_NEED) return;
  const int*  x    = (const int*)d_in[0];
  const void* tok  = d_in[1];
  const void* pos  = d_in[2];
  const void* ln1g = d_in[3];
  const void* ln1b = d_in[4];
  const void* Wq   = d_in[5];
  const void* Wkv  = d_in[6];
  const void* Wp   = d_in[7];
  const void* llng = d_in[8];
  const void* llnb = d_in[9];
  const void* glng = d_in[10];
  const void* glnb = d_in[11];
  const void* Wo   = d_in[12];
  const void* bo   = d_in[13];
  const void* ln2g = d_in[14];
  const void* ln2b = d_in[15];
  const void* W1   = d_in[16];
  const void* b1   = d_in[17];
  const void* W2   = d_in[18];
  const void* b2   = d_in[19];
  const void* lnfg = d_in[20];
  const void* lnfb = d_in[21];
  const void* Wlog = d_in[22];
  const void* blog = d_in[23];
  const void* Wfin = d_in[24];
  const void* bfin = d_in[25];

  char* ws = (char*)d_ws;
  float* h    = (float*)(ws + OFF_H);
  u16* y      = (u16*)(ws + OFF_Y);
  u16* ob     = (u16*)(ws + OFF_Y);
  float* gkF  = (float*)(ws + OFF_GKF);
  float* gvF  = (float*)(ws + OFF_GVF);
  u16* qb     = (u16*)(ws + OFF_Q);
  u16* kv     = (u16*)(ws + OFF_KV);
  u16* gk     = (u16*)(ws + OFF_GK);
  u16* gv     = (u16*)(ws + OFF_GV);
  u16* big    = (u16*)(ws + OFF_BIG);
  float* bigf = (float*)(ws + OFF_BIG);
  u16* gvT    = (u16*)(ws + OFF_KT);
  u16* vT     = (u16*)(ws + OFF_VT);
  u16* wTp    = (u16*)(ws + OFF_WTP);
  u16* sWqT   = (u16*)(ws + OFF_WQT);
  u16* sWkvT  = (u16*)(ws + OFF_WKVT);
  u16* sWoT   = (u16*)(ws + OFF_WOT);
  u16* sW1T   = (u16*)(ws + OFF_W1T);
  u16* sW2T   = (u16*)(ws + OFF_W2T);
  float* part = (float*)(ws + OFF_PART);
  int* flag   = (int*)(ws + OFF_FLAG);

  dim3 tb(32,8);
  detect_kernel<<<dim3(1),dim3(256),0,stream>>>(tok, flag);
  cvtT_kernel<<<dim3(2,8,4),tb,0,stream>>>(Wp, 0, 16384, wTp, 16384, 64, 256, flag);
  embed_kernel<<<dim3(32768),dim3(256),0,stream>>>(x, tok, pos, h, flag);

  for(int l=0;l<4;l++){
    cvtT_kernel<<<dim3(16,16,1),tb,0,stream>>>(Wq,  (long long)l*262144,  0, sWqT,  0, 512, 512,  flag);
    cvtT_kernel<<<dim3(16,32,1),tb,0,stream>>>(Wkv, (long long)l*524288,  0, sWkvT, 0, 512, 1024, flag);
    cvtT_kernel<<<dim3(16,16,1),tb,0,stream>>>(Wo,  (long long)l*262144,  0, sWoT,  0, 512, 512,  flag);
    cvtT_kernel<<<dim3(16,64,1),tb,0,stream>>>(W1,  (long long)l*1048576, 0, sW1T,  0, 512, 2048, flag);
    cvtT_kernel<<<dim3(64,16,1),tb,0,stream>>>(W2,  (long long)l*1048576, 0, sW2T,  0, 2048, 512, flag);

    // y = LN1(h)
    ln512_kernel<<<dim3(16384),dim3(256),0,stream>>>(h, ln1g, ln1b, l*512, y, flag);
    // q = (y@Wq)*SCALE ; kv = y@Wkv
    { Gemm128P p = mk128(y, sWqT, qb, nullptr,0,flag, 512,512,512,512, 0.125f, 0);
      gemm3b_kernel<<<dim3(128,2),512,0,stream>>>(p); }
    { Gemm128P p = mk128(y, sWkvT, kv, nullptr,0,flag, 512,512,512,1024, 1.f, 0);
      gemm3b_kernel<<<dim3(128,4),512,0,stream>>>(p); }
    zerof_kernel<<<dim3(4096),dim3(256),0,stream>>>(gkF, 1048576);
    // p[bh][r][n] = WpT[r,:]·k[bh,n,:]
    { GemmP p = mkg(wTp + (size_t)l*16384, kv, big, nullptr,0,flag, 64,64,1024,4096,
        0,0,0, 4194304LL,64,0, 8388608LL,1048576LL,0, 8,1, 1.f, 0, 0);
      gemm_kernel<<<dim3(4,64,32),256,0,stream>>>(p); }
    softmax4096_kernel<<<dim3(8192),dim3(256),0,stream>>>(big);
    // gk/gv = p@k / p@v via split-K=8 + fp32 atomics, B=kv direct (NN mode).
    { GemmP p = mkg(big, kv, gkF, nullptr,0,flag, 4096,4096,1024,64,
        8388608LL,1048576LL,0, 4194304LL,64,0, 131072LL,16384LL,0, 64,8, 1.f,
        FLAG_CF32|FLAG_ATOMIC|FLAG_NN, 512);
      gemm_kernel<<<dim3(4,1,256),256,0,stream>>>(p); }
    { GemmP p = mkg(big, kv+512, gvF, nullptr,0,flag, 4096,4096,1024,64,
        8388608LL,1048576LL,0, 4194304LL,64,0, 131072LL,16384LL,0, 64,8, 1.f,
        FLAG_CF32|FLAG_ATOMIC|FLAG_NN, 512);
      gemm_kernel<<<dim3(4,1,256),256,0,stream>>>(p); }
    // gLN, lLN
    ln64_kernel<<<dim3(2048),dim3(256),0,stream>>>(gk, gkF, gk, glng, glnb, l*64, 64,1,1, 1,1, flag);
    ln64_kernel<<<dim3(2048),dim3(256),0,stream>>>(gv, gvF, gv, glng, glnb, l*64, 64,1,1, 1,1, flag);
    ln64_kernel<<<dim3(32768),dim3(256),0,stream>>>(kv,     nullptr, kv,     llng, llnb, l*64, 4194304LL,64,1024, 32768,4096, flag);
    ln64_kernel<<<dim3(32768),dim3(256),0,stream>>>(kv+512, nullptr, kv+512, llng, llnb, l*64, 4194304LL,64,1024, 32768,4096, flag);
    // LN'd v^T and gv^T
    transposeB_kernel<<<dim3(128,2,32),tb,0,stream>>>(kv+512, vT, 4194304LL,64,8, 262144LL, 1024, 4096);
    transposeB_kernel<<<dim3(8,2,32),tb,0,stream>>>(gv, gvT, 16384LL,0,1, 16384LL, 64, 256);
    // fused attention -> ob   (32-row tiles: grid 128 x 32)
    { AttnP ap; ap.q=qb; ap.k=kv; ap.gk=gk; ap.vT=vT; ap.gvT=gvT; ap.o=ob;
      attn_kernel<<<dim3(128,32),256,0,stream>>>(ap); }
    // h += o@Wo + bo
    { Gemm128P p = mk128(ob, sWoT, h, bo,l*512,flag, 512,512,512,512, 1.f, FLAG_ACC|FLAG_CF32);
      gemm3b_kernel<<<dim3(128,2),512,0,stream>>>(p); }
    // FFN
    ln512_kernel<<<dim3(16384),dim3(256),0,stream>>>(h, ln2g, ln2b, l*512, y, flag);
    { Gemm128P p = mk128(y, sW1T, big, b1,l*2048,flag, 512,512,512,2048, 1.f, FLAG_GELU);
      gemm3b_kernel<<<dim3(128,8),512,0,stream>>>(p); }
    { Gemm128P p = mk128(big, sW2T, h, b2,l*512,flag, 2048,2048,2048,512, 1.f, FLAG_ACC|FLAG_CF32);
      gemm3b_kernel<<<dim3(128,2),512,0,stream>>>(p); }
  }
  // logits = LN_f(h)@Wlog + blog (fp32 out)
  ln512_kernel<<<dim3(16384),dim3(256),0,stream>>>(h, lnfg, lnfb, 0, y, flag);
  cvtT_kernel<<<dim3(16,16,1),tb,0,stream>>>(Wlog, 0, 0, sWqT, 0, 512, 512, flag);
  { Gemm128P p = mk128(y, sWqT, bigf, blog,0,flag, 512,512,512,512, 1.f, FLAG_CF32);
    gemm3b_kernel<<<dim3(128,2),512,0,stream>>>(p); }
  // final head
  zero40_kernel<<<dim3(1),dim3(64),0,stream>>>(part);
  head_kernel<<<dim3(1024),dim3(256),0,stream>>>(bigf, Wfin, part, flag);
  fin_kernel<<<dim3(1),dim3(64),0,stream>>>(part, bfin, d_out, flag);
}

// Round 6
// 2191.157 us; speedup vs baseline: 1.0548x; 1.0548x over previous
//
#include <hip/hip_runtime.h>
#include <hip/hip_bf16.h>

typedef unsigned short u16;
typedef __attribute__((ext_vector_type(8))) short short8;
typedef __attribute__((ext_vector_type(4))) float floatx4;

#define FLAG_GELU   1
#define FLAG_ACC    2
#define FLAG_NN     4
#define FLAG_CF32   8
#define FLAG_ATOMIC 16

__device__ __forceinline__ float bf2f(u16 u){
  union { unsigned u; float f; } c; c.u = ((unsigned)u)<<16; return c.f;
}
__device__ __forceinline__ u16 f2bf(float f){
  union { float f; unsigned u; } c; c.f = f;
  unsigned r = (c.u + 0x7fffu + ((c.u>>16)&1u))>>16;
  return (u16)r;
}
__device__ __forceinline__ float rdin(const void* base, long long idx, int flagv){
  return flagv ? ((const float*)base)[idx] : bf2f(((const u16*)base)[idx]);
}
// tanh-approx GELU via fast exp: tanh(u) = 1 - 2/(e^{2u}+1); saturates correctly.
__device__ __forceinline__ float fast_gelu(float x){
  float u = 0.7978845608028654f*(x + 0.044715f*x*x*x);
  float e = __expf(2.f*u);
  float t = 1.f - 2.f/(e+1.f);
  return 0.5f*x*(1.f+t);
}

// ---------------- input dtype probe ----------------
__global__ void detect_kernel(const void* tok, int* flag){
  __shared__ int cnt;
  if(threadIdx.x==0) cnt=0;
  __syncthreads();
  float v = fabsf(bf2f(((const u16*)tok)[threadIdx.x]));
  int bad = (v < 1e3f) ? 0 : 1;
  atomicAdd(&cnt, bad);
  __syncthreads();
  if(threadIdx.x==0) *flag = (cnt>0) ? 1 : 0;
}

// ---------------- fused dual-dtype convert + transpose: src[K][N] -> dst[N][K] bf16 ----------------
__global__ void cvtT_kernel(const void* src, long long off0, long long zstride, u16* __restrict__ dst,
    long long dzstride, int K, int N, const int* flag){
  __shared__ float tl[32][33];
  int fl = *flag;
  int k0 = blockIdx.x*32, n0 = blockIdx.y*32;
  long long base = off0 + (long long)blockIdx.z*zstride;
  for(int i=threadIdx.y;i<32;i+=8){
    long long idx = base + (long long)(k0+i)*N + n0 + threadIdx.x;
    tl[i][threadIdx.x] = fl ? ((const float*)src)[idx] : bf2f(((const u16*)src)[idx]);
  }
  __syncthreads();
  u16* dz = dst + (long long)blockIdx.z*dzstride;
  for(int i=threadIdx.y;i<32;i+=8)
    dz[(long long)(n0+i)*K + k0 + threadIdx.x] = f2bf(tl[threadIdx.x][i]);
}

// ---------------- bf16 ws->ws transpose, batched ----------------
__global__ void transposeB_kernel(const u16* __restrict__ in, u16* __restrict__ out,
    long long izs0, long long izs1, int zd, long long ozstride, int ldin, int ldout){
  __shared__ u16 tl[32][33];
  int z = blockIdx.z; int z0 = z/zd, z1 = z - z0*zd;
  const u16* ip = in + z0*izs0 + z1*izs1;
  u16* op = out + (long long)z*ozstride;
  int r0 = blockIdx.x*32, c0 = blockIdx.y*32;
  for(int i=threadIdx.y;i<32;i+=8)
    tl[i][threadIdx.x] = ip[(long long)(r0+i)*ldin + c0 + threadIdx.x];
  __syncthreads();
  for(int i=threadIdx.y;i<32;i+=8)
    op[(long long)(c0+i)*ldout + r0 + threadIdx.x] = tl[threadIdx.x][i];
}

// ---------------- fused LN(64) + transpose for local v: raw kv -> vT ----------------
// v row (b,h,n) = kv[b*4194304 + n*1024 + 512 + h*64 .. +64]; out vT[bh][64][4096].
// Block: 32 n-rows x 64 d. Thread t: row r=t>>3, seg=t&7 (8 elems); stats via
// 8-lane shfl_xor. Write phase: thread t writes d=t>>2, n-chunk (t&3)*8 (uint4).
__global__ __launch_bounds__(256) void lnT_kernel(const u16* __restrict__ kv, u16* __restrict__ vT,
    const void* g, const void* b_, int goff, const int* flag){
  __shared__ u16 tl[32][72];
  int flagv = *flag;
  int nt = blockIdx.x;          // 0..127 n-tile
  int bh = blockIdx.y;          // 0..31
  int bb = bh>>3, hh = bh&7;
  int t = threadIdx.x;
  int r = t>>3, seg = t&7;
  const u16* src = kv + (long long)bb*4194304 + (long long)(nt*32 + r)*1024 + 512 + hh*64 + seg*8;
  u16 buf[8]; *(uint4*)buf = *(const uint4*)src;
  float x[8]; float s=0.f, sq=0.f;
  #pragma unroll
  for(int j=0;j<8;j++){ x[j]=bf2f(buf[j]); s+=x[j]; sq+=x[j]*x[j]; }
  s  += __shfl_xor(s,1);  s  += __shfl_xor(s,2);  s  += __shfl_xor(s,4);
  sq += __shfl_xor(sq,1); sq += __shfl_xor(sq,2); sq += __shfl_xor(sq,4);
  float mu = s*(1.f/64.f), var = sq*(1.f/64.f)-mu*mu;
  float inv = rsqrtf(var+1e-5f);
  #pragma unroll
  for(int j=0;j<8;j++){
    int d = seg*8+j;
    tl[r][d] = f2bf((x[j]-mu)*inv*rdin(g,goff+d,flagv) + rdin(b_,goff+d,flagv));
  }
  __syncthreads();
  int d = t>>2, nc = (t&3)*8;
  u16 ob[8];
  #pragma unroll
  for(int j=0;j<8;j++) ob[j] = tl[nc+j][d];
  *(uint4*)(vT + (long long)bh*262144 + (long long)d*4096 + nt*32 + nc) = *(uint4*)ob;
}

__global__ __launch_bounds__(256) void zerof_kernel(float* p, int n){
  int i = blockIdx.x*256 + threadIdx.x;
  if(i<n) p[i]=0.f;
}

// ---------------- 64x64 batched GEMM (attention pre-stage shapes) ----------------
struct GemmP {
  const u16* A; const u16* B; float* Cf; u16* Ch;
  const void* bias; int biasOff; const int* dflag;
  int K, lda, ldb, ldc;
  long long sA0,sA1,sA2,sB0,sB1,sB2,sC0,sC1,sC2;
  int d0,d1; float alpha; int flags; int ksplit;
};

__global__ __launch_bounds__(256) void gemm_kernel(GemmP p){
  __shared__ __align__(16) u16 As[64][40];
  __shared__ __align__(16) u16 Bs[64][40];
  int z = blockIdx.z;
  int i0 = z / p.d0; int rem = z - i0*p.d0; int i1 = rem / p.d1; int i2 = rem - i1*p.d1;
  const u16* A  = p.A + i0*p.sA0 + i1*p.sA1 + i2*p.sA2;
  const u16* Bp = p.B + i0*p.sB0 + i1*p.sB1 + i2*p.sB2;
  long long cb = i0*p.sC0 + i1*p.sC1 + i2*p.sC2;
  int kbeg = 0, kend = p.K;
  if(p.ksplit){ kbeg = i2*p.ksplit; kend = kbeg + p.ksplit; }
  int m0 = blockIdx.x*64, n0 = blockIdx.y*64;
  int t = threadIdx.x, lane = t&63, wave = t>>6;
  int wm = (wave>>1)*32, wn = (wave&1)*32;
  int quad = lane>>4, l16 = lane&15;
  floatx4 zero4 = {0.f,0.f,0.f,0.f};
  floatx4 acc00=zero4, acc01=zero4, acc10=zero4, acc11=zero4;
  int sr = t>>2, sc = (t&3)*8;
  int bkr = t>>3, bnc = (t&7)*8;
  bool nn = (p.flags & FLAG_NN);
  for(int k0=kbeg;k0<kend;k0+=32){
    uint4 av = *(const uint4*)(A + (long long)(m0+sr)*p.lda + (k0+sc));
    uint4 bv;
    if(nn) bv = *(const uint4*)(Bp + (long long)(k0+bkr)*p.ldb + (n0+bnc));
    else   bv = *(const uint4*)(Bp + (long long)(n0+sr)*p.ldb + (k0+sc));
    *(uint4*)&As[sr][sc] = av;
    if(nn){
      u16 tmp[8]; *(uint4*)tmp = bv;
      #pragma unroll
      for(int j=0;j<8;j++) Bs[bnc+j][bkr] = tmp[j];
    } else {
      *(uint4*)&Bs[sr][sc] = bv;
    }
    __syncthreads();
    short8 a0 = *(const short8*)&As[wm+l16][quad*8];
    short8 a1 = *(const short8*)&As[wm+16+l16][quad*8];
    short8 b0 = *(const short8*)&Bs[wn+l16][quad*8];
    short8 b1 = *(const short8*)&Bs[wn+16+l16][quad*8];
    acc00 = __builtin_amdgcn_mfma_f32_16x16x32_bf16(a0,b0,acc00,0,0,0);
    acc01 = __builtin_amdgcn_mfma_f32_16x16x32_bf16(a0,b1,acc01,0,0,0);
    acc10 = __builtin_amdgcn_mfma_f32_16x16x32_bf16(a1,b0,acc10,0,0,0);
    acc11 = __builtin_amdgcn_mfma_f32_16x16x32_bf16(a1,b1,acc11,0,0,0);
    __syncthreads();
  }
  int flagv = p.bias ? *p.dflag : 0;
  #pragma unroll
  for(int mi=0;mi<2;mi++){
    #pragma unroll
    for(int ni=0;ni<2;ni++){
      floatx4 a = (mi==0)?((ni==0)?acc00:acc01):((ni==0)?acc10:acc11);
      int cg = n0 + wn + ni*16 + l16;
      float bv_ = p.bias ? rdin(p.bias, (long long)p.biasOff + cg, flagv) : 0.f;
      #pragma unroll
      for(int e=0;e<4;e++){
        int rg = m0 + wm + mi*16 + quad*4 + e;
        float v = a[e]*p.alpha + bv_;
        if(p.flags & FLAG_GELU) v = fast_gelu(v);
        long long ci = cb + (long long)rg*p.ldc + cg;
        if(p.flags & FLAG_ATOMIC){
          atomicAdd(&p.Cf[ci], v);
        } else if(p.flags & FLAG_CF32){
          float o2 = v; if(p.flags&FLAG_ACC) o2 += p.Cf[ci];
          p.Cf[ci] = o2;
        } else {
          float o2 = v; if(p.flags&FLAG_ACC) o2 += bf2f(p.Ch[ci]);
          p.Ch[ci] = f2bf(o2);
        }
      }
    }
  }
}

// ---------------- big-GEMM params (shared by 2-phase kernels) ----------------
struct Gemm128P {
  const u16* A; const u16* B; float* Cf; u16* Ch;
  const void* bias; int biasOff; const int* dflag;
  int K, lda, ldb, ldc; float alpha; int flags;
};

// ---------------- BM x 256 GEMM, BK=64, double-buffered 2-phase schedule ----------------
// 512 threads = 8 waves (2M x 4N). Per wave: (BM/2) x 64 output.
// T2 swizzle (rule #21): LDS dest linear; global SOURCE column XOR-permuted
// within each 128B row; ds_read applies the same XOR -> conflict-free (r3: 9.4M->0).
// T1 XCD swizzle: y-major flat id, bijective chunking (all grids %8==0) so each
// XCD's L2 holds a contiguous set of A-panels + the B-panels it needs.
template<int BM>
__global__ __launch_bounds__(512) void gemm2ph_kernel(Gemm128P p){
  constexpr int NA   = BM/64;             // A-stage gload_lds instrs per K-tile
  constexpr int HH   = BM/2;              // per-wave M rows
  constexpr int MI   = HH/16;             // M fragments per wave
  constexpr int ABUF = BM*64;             // u16 per A buffer
  constexpr int LDSZ = (BM==256) ? 69632 : 49152;  // max(dbuf, epilogue) u16
  __shared__ __align__(16) u16 lds[LDSZ];
  u16* As = lds;                          // 2 bufs x ABUF
  u16* Bs = lds + 2*ABUF;                 // 2 bufs x 16384
  int gy = gridDim.y;
  int nw = gridDim.x*gy;
  int wg = blockIdx.x*gy + blockIdx.y;    // y-major flat id
  int q8 = nw>>3;
  int swz = (wg&7)*q8 + (wg>>3);          // XCD-contiguous chunks (nw%8==0)
  int m0 = (swz/gy)*BM, n0 = (swz - (swz/gy)*gy)*256;
  int t = threadIdx.x, lane = t&63, wave = t>>6;
  int quad = lane>>4, l16 = lane&15;
  int wr = wave>>2, wc = wave&3;
  int rowA = t>>3;
  int colk = (((t&7) ^ (rowA&7)))*8;      // inverse-swizzled source column
  const u16* Asrc[NA];
  const u16* Bsrc[4];
  #pragma unroll
  for(int q=0;q<NA;q++) Asrc[q] = p.A + (long long)(m0 + q*64 + rowA)*p.lda + colk;
  #pragma unroll
  for(int q=0;q<4;q++)  Bsrc[q] = p.B + (long long)(n0 + q*64 + rowA)*p.ldb + colk;
  int nk = p.K >> 6;
  floatx4 acc[MI][4] = {};

  auto stage = [&](int buf, int k0){
    #pragma unroll
    for(int q=0;q<NA;q++)
      __builtin_amdgcn_global_load_lds(
        (const __attribute__((address_space(1))) unsigned int*)(Asrc[q] + k0),
        (__attribute__((address_space(3))) unsigned int*)(As + buf*ABUF + q*4096 + wave*512),
        16, 0, 0);
    #pragma unroll
    for(int q=0;q<4;q++)
      __builtin_amdgcn_global_load_lds(
        (const __attribute__((address_space(1))) unsigned int*)(Bsrc[q] + k0),
        (__attribute__((address_space(3))) unsigned int*)(Bs + buf*16384 + q*4096 + wave*512),
        16, 0, 0);
  };

  stage(0, 0);
  __syncthreads();                        // prologue drain: buf0 resident
  int sw = l16&7;                         // read-side XOR (row&7 == l16&7 here)
  for(int kt=0; kt<nk; ++kt){
    int cur = kt&1;
    if(kt+1 < nk) stage(cur^1, (kt+1)*64);  // issue next-tile loads FIRST
    const u16* Ab = As + cur*ABUF;
    const u16* Bb = Bs + cur*16384;
    #pragma unroll
    for(int ks=0; ks<2; ks++){
      short8 a[MI], b[4];
      #pragma unroll
      for(int i=0;i<MI;i++)
        a[i] = *(const short8*)&Ab[(wr*HH + i*16 + l16)*64 + ((((ks<<2)|quad) ^ sw)<<3)];
      #pragma unroll
      for(int j=0;j<4;j++)
        b[j] = *(const short8*)&Bb[(wc*64 + j*16 + l16)*64 + ((((ks<<2)|quad) ^ sw)<<3)];
      #pragma unroll
      for(int i=0;i<MI;i++)
        #pragma unroll
        for(int j=0;j<4;j++)
          acc[i][j] = __builtin_amdgcn_mfma_f32_16x16x32_bf16(a[i], b[j], acc[i][j],0,0,0);
    }
    __syncthreads();                      // reads done by all waves + next buf landed
  }

  int flagv = p.bias ? *p.dflag : 0;
  if(!(p.flags & FLAG_CF32)){
    // bf16 out: transpose tile through LDS (wave-private), store 16B lines.
    u16* Ct = lds + wave*(HH*68);
    #pragma unroll
    for(int j=0;j<4;j++){
      int cg = n0 + wc*64 + j*16 + l16;
      float bv_ = p.bias ? rdin(p.bias, (long long)p.biasOff + cg, flagv) : 0.f;
      #pragma unroll
      for(int i=0;i<MI;i++){
        #pragma unroll
        for(int e=0;e<4;e++){
          float v = acc[i][j][e]*p.alpha + bv_;
          if(p.flags & FLAG_GELU) v = fast_gelu(v);
          Ct[(i*16 + quad*4 + e)*68 + j*16 + l16] = f2bf(v);
        }
      }
    }
    int rsub = lane>>3, csub = (lane&7)*8;
    #pragma unroll
    for(int rr=0; rr<HH/8; rr++){
      int row = rr*8 + rsub;
      uint4 v = *(const uint4*)&Ct[row*68 + csub];
      *(uint4*)(p.Ch + (long long)(m0 + wr*HH + row)*p.ldc + (n0 + wc*64 + csub)) = v;
    }
  } else {
    #pragma unroll
    for(int j=0;j<4;j++){
      int cg = n0 + wc*64 + j*16 + l16;
      float bv_ = p.bias ? rdin(p.bias, (long long)p.biasOff + cg, flagv) : 0.f;
      #pragma unroll
      for(int i=0;i<MI;i++){
        #pragma unroll
        for(int e=0;e<4;e++){
          int rg = m0 + wr*HH + i*16 + quad*4 + e;
          float v = acc[i][j][e]*p.alpha + bv_;
          if(p.flags & FLAG_GELU) v = fast_gelu(v);
          long long ci = (long long)rg*p.ldc + cg;
          float o2 = v; if(p.flags&FLAG_ACC) o2 += p.Cf[ci];
          p.Cf[ci] = o2;
        }
      }
    }
  }
}

// ---------------- fused window attention (occupancy-optimized) ----------------
struct AttnP {
  const u16* q;    // [B][4096][512] (pre-scaled)
  const u16* k;    // LN'd kv base [B][4096][1024], head offset h*64
  const u16* gk;   // [bh][256][64] (LN'd)
  const u16* vT;   // [bh][64][4096] (LN'd local v, transposed)
  const u16* gvT;  // [bh][64][256]  (LN'd global v, transposed)
  u16* o;          // [B][4096][512]
};

__global__ __launch_bounds__(256) void attn_kernel(AttnP p){
  __shared__ __align__(16) u16 S[32*392];   // 32 rows x 392 stride
  __shared__ float ssum[32];
  const int SST = 392;
  int qb = blockIdx.x;          // 0..127 : 32-row q tile
  int bh = blockIdx.y;
  int b = bh>>3, hh = bh&7;
  int w = qb>>2;                // 128-row window this tile belongs to
  int t = threadIdx.x, lane = t&63, wave = t>>6;
  int quad = lane>>4, l16 = lane&15;
  int mbase = qb*32;
  short8 aq[2][2];
  #pragma unroll
  for(int mt=0;mt<2;mt++)
    #pragma unroll
    for(int kc=0;kc<2;kc++)
      aq[mt][kc] = *(const short8*)(p.q + ((long long)b*4096 + mbase + mt*16 + l16)*512 + hh*64 + kc*32 + quad*8);
  #pragma unroll
  for(int i=0;i<6;i++){
    int ct = wave*6 + i;
    short8 bf0, bf1;
    if(ct<8){
      const u16* kr = p.k + ((long long)b*4096 + w*128 + ct*16 + l16)*1024 + hh*64;
      bf0 = *(const short8*)(kr + quad*8);
      bf1 = *(const short8*)(kr + 32 + quad*8);
    } else {
      const u16* gr = p.gk + ((long long)bh*256 + (ct-8)*16 + l16)*64;
      bf0 = *(const short8*)(gr + quad*8);
      bf1 = *(const short8*)(gr + 32 + quad*8);
    }
    #pragma unroll
    for(int mt=0;mt<2;mt++){
      floatx4 acc = {0.f,0.f,0.f,0.f};
      acc = __builtin_amdgcn_mfma_f32_16x16x32_bf16(aq[mt][0], bf0, acc,0,0,0);
      acc = __builtin_amdgcn_mfma_f32_16x16x32_bf16(aq[mt][1], bf1, acc,0,0,0);
      #pragma unroll
      for(int e=0;e<4;e++)
        S[(mt*16 + quad*4 + e)*SST + ct*16 + l16] = f2bf(acc[e]);
    }
  }
  __syncthreads();
  {
    int r = t>>3, seg = t&7;
    u16* Srow = S + r*SST + seg*48;
    u16 buf[48];
    #pragma unroll
    for(int it=0; it<6; it++)
      *(uint4*)(buf + it*8) = *(const uint4*)(Srow + it*8);
    float mmax = -3.4e38f;
    #pragma unroll
    for(int j=0;j<48;j++) mmax = fmaxf(mmax, bf2f(buf[j]));
    mmax = fmaxf(mmax, __shfl_xor(mmax, 1));
    mmax = fmaxf(mmax, __shfl_xor(mmax, 2));
    mmax = fmaxf(mmax, __shfl_xor(mmax, 4));
    float s = 0.f;
    #pragma unroll
    for(int j=0;j<48;j++){ float e_ = __expf(bf2f(buf[j]) - mmax); s += e_; buf[j] = f2bf(e_); }
    #pragma unroll
    for(int it=0; it<6; it++)
      *(uint4*)(Srow + it*8) = *(const uint4*)(buf + it*8);
    s += __shfl_xor(s, 1);
    s += __shfl_xor(s, 2);
    s += __shfl_xor(s, 4);
    if(seg==0) ssum[r] = 1.f/s;
  }
  __syncthreads();
  int dt = wave;
  floatx4 oacc[2] = {};
  for(int kc=0; kc<12; kc++){
    short8 ap0 = *(const short8*)(S + (l16)*SST + kc*32 + quad*8);
    short8 ap1 = *(const short8*)(S + (16 + l16)*SST + kc*32 + quad*8);
    short8 bv;
    if(kc<4)
      bv = *(const short8*)(p.vT + (long long)bh*262144 + (dt*16+l16)*4096 + w*128 + kc*32 + quad*8);
    else
      bv = *(const short8*)(p.gvT + (long long)bh*16384 + (dt*16+l16)*256 + (kc-4)*32 + quad*8);
    oacc[0] = __builtin_amdgcn_mfma_f32_16x16x32_bf16(ap0, bv, oacc[0],0,0,0);
    oacc[1] = __builtin_amdgcn_mfma_f32_16x16x32_bf16(ap1, bv, oacc[1],0,0,0);
  }
  #pragma unroll
  for(int mt=0;mt<2;mt++){
    #pragma unroll
    for(int e=0;e<4;e++){
      int row = mt*16 + quad*4 + e;
      float inv = ssum[row];
      p.o[((long long)b*4096 + mbase + row)*512 + hh*64 + dt*16 + l16] = f2bf(oacc[mt][e]*inv);
    }
  }
}

// ---------------- embed ----------------
__global__ __launch_bounds__(256) void embed_kernel(const int* __restrict__ x, const void* tok,
    const void* pos, float* __restrict__ h, const int* flag){
  int i = blockIdx.x*256 + threadIdx.x;
  int flagv = *flag;
  int d = i & 511;
  int n = (i>>9) & 4095;
  int bn = i>>9;
  int tid2 = x[bn];
  h[i] = rdin(tok, (long long)tid2*512 + d, flagv) + rdin(pos, (long long)n*512 + d, flagv);
}

// ---------------- LN over 512 (fp32 in, bf16 out) ----------------
__global__ __launch_bounds__(256) void ln512_kernel(const float* __restrict__ h,
    const void* g, const void* b, int goff, u16* __restrict__ y, const int* flag){
  int row = blockIdx.x;
  int flagv = *flag;
  const float* hr = h + (size_t)row*512;
  int t = threadIdx.x;
  float x0 = hr[t], x1 = hr[t+256];
  float s1 = x0+x1, s2 = x0*x0+x1*x1;
  for(int o=32;o>0;o>>=1){ s1 += __shfl_down(s1,o,64); s2 += __shfl_down(s2,o,64); }
  __shared__ float sh1[4], sh2[4];
  int wv=t>>6, ln=t&63;
  if(ln==0){ sh1[wv]=s1; sh2[wv]=s2; }
  __syncthreads();
  float st = sh1[0]+sh1[1]+sh1[2]+sh1[3];
  float qt = sh2[0]+sh2[1]+sh2[2]+sh2[3];
  float mu = st*(1.f/512.f);
  float var = qt*(1.f/512.f) - mu*mu;
  float inv = rsqrtf(var+1e-5f);
  u16* yr = y + (size_t)row*512;
  yr[t]     = f2bf((x0-mu)*inv*rdin(g,goff+t,flagv)     + rdin(b,goff+t,flagv));
  yr[t+256] = f2bf((x1-mu)*inv*rdin(g,goff+t+256,flagv) + rdin(b,goff+t+256,flagv));
}

// ---------------- LN over 64; optional fp32 input; strided ----------------
__global__ __launch_bounds__(256) void ln64_kernel(const u16* __restrict__ in, const float* __restrict__ inF,
    u16* __restrict__ out, const void* g, const void* b, int goff,
    long long s0, long long s1v, long long s2v, int d0, int d1, const int* flag){
  int r = blockIdx.x*4 + (threadIdx.x>>6);
  int ln = threadIdx.x&63;
  int flagv = *flag;
  int i0 = r/d0; int rem = r - i0*d0; int i1 = rem/d1; int i2 = rem - i1*d1;
  long long off = i0*s0 + i1*s1v + i2*s2v;
  float x = inF ? inF[off+ln] : bf2f(in[off + ln]);
  float s = x, sq = x*x;
  for(int o=32;o>0;o>>=1){ s += __shfl_down(s,o,64); sq += __shfl_down(sq,o,64); }
  s = __shfl(s,0,64); sq = __shfl(sq,0,64);
  float mu = s*(1.f/64.f), var = sq*(1.f/64.f)-mu*mu;
  float inv = rsqrtf(var+1e-5f);
  out[off + ln] = f2bf((x-mu)*inv*rdin(g,goff+ln,flagv) + rdin(b,goff+ln,flagv));
}

// ---------------- softmax over 4096 (bf16, in place) ----------------
__global__ __launch_bounds__(256) void softmax4096_kernel(u16* __restrict__ p){
  u16* pr = p + (size_t)blockIdx.x*4096;
  int t = threadIdx.x;
  u16 tmp[16];
  *(uint4*)tmp     = *(const uint4*)(pr + t*16);
  *(uint4*)(tmp+8) = *(const uint4*)(pr + t*16 + 8);
  float xs[16]; float m=-3.4e38f;
  #pragma unroll
  for(int i=0;i<16;i++){ xs[i]=bf2f(tmp[i]); m=fmaxf(m,xs[i]); }
  for(int o=32;o>0;o>>=1) m = fmaxf(m, __shfl_down(m,o,64));
  __shared__ float sm[4]; __shared__ float sv[4];
  int wv=t>>6, ln=t&63;
  if(ln==0) sm[wv]=m;
  __syncthreads();
  m = fmaxf(fmaxf(sm[0],sm[1]),fmaxf(sm[2],sm[3]));
  float s=0;
  #pragma unroll
  for(int i=0;i<16;i++){ xs[i]=__expf(xs[i]-m); s+=xs[i]; }
  for(int o=32;o>0;o>>=1) s += __shfl_down(s,o,64);
  if(ln==0) sv[wv]=s;
  __syncthreads();
  s = sv[0]+sv[1]+sv[2]+sv[3];
  float inv = 1.f/s;
  #pragma unroll
  for(int i=0;i<16;i++) tmp[i]=f2bf(xs[i]*inv);
  *(uint4*)(pr + t*16)     = *(uint4*)tmp;
  *(uint4*)(pr + t*16 + 8) = *(uint4*)(tmp+8);
}

// ---------------- head ----------------
__global__ void zero40_kernel(float* p){ if(threadIdx.x<40) p[threadIdx.x]=0.f; }

// out[b][c] = sum_j logits[b][j] * W[j][c].  Grid = 1024 blocks, each owns 2048
// CONSECUTIVE W rows and all 4 batches (W read exactly once, coalesced).
__global__ __launch_bounds__(256) void head_kernel(const float* __restrict__ logits,
    const void* wfin, float* __restrict__ part, const int* flag){
  __shared__ __align__(16) u16 Wl[20480];   // 2048 rows x 10 bf16
  __shared__ float redl[4][40];
  int flagv = *flag;
  int t = threadIdx.x;
  long long rbase = (long long)blockIdx.x*2048;
  float acc[4][10];
  #pragma unroll
  for(int b4=0;b4<4;b4++)
    #pragma unroll
    for(int c=0;c<10;c++) acc[b4][c]=0.f;

  if(!flagv){
    const uint4* src = (const uint4*)((const u16*)wfin + rbase*10);
    uint4* dst = (uint4*)Wl;
    #pragma unroll
    for(int i=0;i<10;i++) dst[t + i*256] = src[t + i*256];
    __syncthreads();
    const unsigned* Wd = (const unsigned*)Wl;
    #pragma unroll
    for(int i=0;i<8;i++){
      int r = t + i*256;
      float l0 = logits[rbase + r];
      float l1 = logits[2097152 + rbase + r];
      float l2 = logits[4194304 + rbase + r];
      float l3 = logits[6291456 + rbase + r];
      #pragma unroll
      for(int k2=0;k2<5;k2++){
        unsigned d = Wd[r*5 + k2];
        float w0 = bf2f((u16)(d & 0xffffu));
        float w1 = bf2f((u16)(d >> 16));
        acc[0][2*k2]   += l0*w0; acc[0][2*k2+1] += l0*w1;
        acc[1][2*k2]   += l1*w0; acc[1][2*k2+1] += l1*w1;
        acc[2][2*k2]   += l2*w0; acc[2][2*k2+1] += l2*w1;
        acc[3][2*k2]   += l3*w0; acc[3][2*k2+1] += l3*w1;
      }
    }
  } else {
    #pragma unroll
    for(int i=0;i<8;i++){
      int r = t + i*256;
      float l0 = logits[rbase + r];
      float l1 = logits[2097152 + rbase + r];
      float l2 = logits[4194304 + rbase + r];
      float l3 = logits[6291456 + rbase + r];
      const float* wr = (const float*)wfin + (rbase + r)*10;
      #pragma unroll
      for(int c=0;c<10;c++){
        float w = wr[c];
        acc[0][c] += l0*w; acc[1][c] += l1*w; acc[2][c] += l2*w; acc[3][c] += l3*w;
      }
    }
  }
  int wv = t>>6, ln = t&63;
  #pragma unroll
  for(int b4=0;b4<4;b4++)
    #pragma unroll
    for(int c=0;c<10;c++){
      float v = acc[b4][c];
      for(int o=32;o>0;o>>=1) v += __shfl_down(v,o,64);
      if(ln==0) redl[wv][b4*10+c] = v;
    }
  __syncthreads();
  if(t<40) atomicAdd(&part[t], redl[0][t]+redl[1][t]+redl[2][t]+redl[3][t]);
}

__global__ void fin_kernel(const float* __restrict__ part, const void* bfin, void* out, const int* flag){
  int i=threadIdx.x;
  int flagv = *flag;
  if(i<40){
    float r = part[i] + rdin(bfin, i%10, flagv);
    if(flagv) ((float*)out)[i] = r;
    else      ((u16*)out)[i]   = f2bf(r);
  }
}

// ---------------- workspace layout (bytes) — total ~209.8 MB ----------------
static const size_t OFF_H    = 0;
static const size_t OFF_Y    = 33554432;
static const size_t OFF_GKF  = 33554432;
static const size_t OFF_GVF  = 35651584;
static const size_t OFF_Q    = 50331648;
static const size_t OFF_KV   = 67108864;
static const size_t OFF_GK   = 100663296;
static const size_t OFF_GV   = 101711872;
static const size_t OFF_BIG  = 102760448;
static const size_t OFF_KT   = 169869312;   // gvT
static const size_t OFF_VT   = 186646528;   // LN'd v^T
static const size_t OFF_WTP  = 203423744;
static const size_t OFF_WQT  = 203554816;
static const size_t OFF_WKVT = 204079104;
static const size_t OFF_WOT  = 205127680;
static const size_t OFF_W1T  = 205651968;
static const size_t OFF_W2T  = 207749120;
static const size_t OFF_PART = 209846272;
static const size_t OFF_FLAG = 209846528;
static const size_t WS_NEED  = 209846784;

static inline GemmP mkg(const void*A,const void*B,void*C,const void*bias,int biasOff,const int* dflag,
  int K,int lda,int ldb,int ldc,
  long long a0,long long a1,long long a2,long long b0,long long b1,long long b2,
  long long c0,long long c1,long long c2,int d0,int d1,float alpha,int flags,int ksplit){
  GemmP p; p.A=(const u16*)A; p.B=(const u16*)B;
  p.Cf=(float*)C; p.Ch=(u16*)C; p.bias=bias; p.biasOff=biasOff; p.dflag=dflag;
  p.K=K;p.lda=lda;p.ldb=ldb;p.ldc=ldc;
  p.sA0=a0;p.sA1=a1;p.sA2=a2;p.sB0=b0;p.sB1=b1;p.sB2=b2;p.sC0=c0;p.sC1=c1;p.sC2=c2;
  p.d0=d0;p.d1=d1;p.alpha=alpha;p.flags=flags;p.ksplit=ksplit; return p;
}
static inline Gemm128P mk128(const void*A,const void*B,void*C,const void*bias,int biasOff,const int* dflag,
  int K,int lda,int ldb,int ldc,float alpha,int flags){
  Gemm128P p; p.A=(const u16*)A; p.B=(const u16*)B;
  p.Cf=(float*)C; p.Ch=(u16*)C; p.bias=bias; p.biasOff=biasOff; p.dflag=dflag;
  p.K=K;p.lda=lda;p.ldb=ldb;p.ldc=ldc;p.alpha=alpha;p.flags=flags; return p;
}

extern "C" void kernel_launch(void* const* d_in, const int* in_sizes, int n_in,
                              void* d_out, int out_size, void* d_ws, size_t ws_size,
                              hipStream_t stream){
  (void)in_sizes;(void)n_in;(void)out_size;
  if(ws_size < WS_NEED) return;
  const int*  x    = (const int*)d_in[0];
  const void* tok  = d_in[1];
  const void* pos  = d_in[2];
  const void* ln1g = d_in[3];
  const void* ln1b = d_in[4];
  const void* Wq   = d_in[5];
  const void* Wkv  = d_in[6];
  const void* Wp   = d_in[7];
  const void* llng = d_in[8];
  const void* llnb = d_in[9];
  const void* glng = d_in[10];
  const void* glnb = d_in[11];
  const void* Wo   = d_in[12];
  const void* bo   = d_in[13];
  const void* ln2g = d_in[14];
  const void* ln2b = d_in[15];
  const void* W1   = d_in[16];
  const void* b1   = d_in[17];
  const void* W2   = d_in[18];
  const void* b2   = d_in[19];
  const void* lnfg = d_in[20];
  const void* lnfb = d_in[21];
  const void* Wlog = d_in[22];
  const void* blog = d_in[23];
  const void* Wfin = d_in[24];
  const void* bfin = d_in[25];

  char* ws = (char*)d_ws;
  float* h    = (float*)(ws + OFF_H);
  u16* y      = (u16*)(ws + OFF_Y);
  u16* ob     = (u16*)(ws + OFF_Y);
  float* gkF  = (float*)(ws + OFF_GKF);
  float* gvF  = (float*)(ws + OFF_GVF);
  u16* qb     = (u16*)(ws + OFF_Q);
  u16* kv     = (u16*)(ws + OFF_KV);
  u16* gk     = (u16*)(ws + OFF_GK);
  u16* gv     = (u16*)(ws + OFF_GV);
  u16* big    = (u16*)(ws + OFF_BIG);
  float* bigf = (float*)(ws + OFF_BIG);
  u16* gvT    = (u16*)(ws + OFF_KT);
  u16* vT     = (u16*)(ws + OFF_VT);
  u16* wTp    = (u16*)(ws + OFF_WTP);
  u16* sWqT   = (u16*)(ws + OFF_WQT);
  u16* sWkvT  = (u16*)(ws + OFF_WKVT);
  u16* sWoT   = (u16*)(ws + OFF_WOT);
  u16* sW1T   = (u16*)(ws + OFF_W1T);
  u16* sW2T   = (u16*)(ws + OFF_W2T);
  float* part = (float*)(ws + OFF_PART);
  int* flag   = (int*)(ws + OFF_FLAG);

  dim3 tb(32,8);
  detect_kernel<<<dim3(1),dim3(256),0,stream>>>(tok, flag);
  cvtT_kernel<<<dim3(2,8,4),tb,0,stream>>>(Wp, 0, 16384, wTp, 16384, 64, 256, flag);
  embed_kernel<<<dim3(32768),dim3(256),0,stream>>>(x, tok, pos, h, flag);

  for(int l=0;l<4;l++){
    cvtT_kernel<<<dim3(16,16,1),tb,0,stream>>>(Wq,  (long long)l*262144,  0, sWqT,  0, 512, 512,  flag);
    cvtT_kernel<<<dim3(16,32,1),tb,0,stream>>>(Wkv, (long long)l*524288,  0, sWkvT, 0, 512, 1024, flag);
    cvtT_kernel<<<dim3(16,16,1),tb,0,stream>>>(Wo,  (long long)l*262144,  0, sWoT,  0, 512, 512,  flag);
    cvtT_kernel<<<dim3(16,64,1),tb,0,stream>>>(W1,  (long long)l*1048576, 0, sW1T,  0, 512, 2048, flag);
    cvtT_kernel<<<dim3(64,16,1),tb,0,stream>>>(W2,  (long long)l*1048576, 0, sW2T,  0, 2048, 512, flag);

    // y = LN1(h)
    ln512_kernel<<<dim3(16384),dim3(256),0,stream>>>(h, ln1g, ln1b, l*512, y, flag);
    // q = (y@Wq)*SCALE ; kv = y@Wkv
    { Gemm128P p = mk128(y, sWqT, qb, nullptr,0,flag, 512,512,512,512, 0.125f, 0);
      gemm2ph_kernel<128><<<dim3(128,2),512,0,stream>>>(p); }
    { Gemm128P p = mk128(y, sWkvT, kv, nullptr,0,flag, 512,512,512,1024, 1.f, 0);
      gemm2ph_kernel<256><<<dim3(64,4),512,0,stream>>>(p); }
    zerof_kernel<<<dim3(4096),dim3(256),0,stream>>>(gkF, 1048576);
    // p[bh][r][n] = WpT[r,:]·k[bh,n,:]
    { GemmP p = mkg(wTp + (size_t)l*16384, kv, big, nullptr,0,flag, 64,64,1024,4096,
        0,0,0, 4194304LL,64,0, 8388608LL,1048576LL,0, 8,1, 1.f, 0, 0);
      gemm_kernel<<<dim3(4,64,32),256,0,stream>>>(p); }
    softmax4096_kernel<<<dim3(8192),dim3(256),0,stream>>>(big);
    // gk/gv = p@k / p@v via split-K=8 + fp32 atomics, B=kv direct (NN mode).
    { GemmP p = mkg(big, kv, gkF, nullptr,0,flag, 4096,4096,1024,64,
        8388608LL,1048576LL,0, 4194304LL,64,0, 131072LL,16384LL,0, 64,8, 1.f,
        FLAG_CF32|FLAG_ATOMIC|FLAG_NN, 512);
      gemm_kernel<<<dim3(4,1,256),256,0,stream>>>(p); }
    { GemmP p = mkg(big, kv+512, gvF, nullptr,0,flag, 4096,4096,1024,64,
        8388608LL,1048576LL,0, 4194304LL,64,0, 131072LL,16384LL,0, 64,8, 1.f,
        FLAG_CF32|FLAG_ATOMIC|FLAG_NN, 512);
      gemm_kernel<<<dim3(4,1,256),256,0,stream>>>(p); }
    // gLN; local k LN in place; local v LN fused into transpose (lnT)
    ln64_kernel<<<dim3(2048),dim3(256),0,stream>>>(gk, gkF, gk, glng, glnb, l*64, 64,1,1, 1,1, flag);
    ln64_kernel<<<dim3(2048),dim3(256),0,stream>>>(gv, gvF, gv, glng, glnb, l*64, 64,1,1, 1,1, flag);
    ln64_kernel<<<dim3(32768),dim3(256),0,stream>>>(kv,     nullptr, kv,     llng, llnb, l*64, 4194304LL,64,1024, 32768,4096, flag);
    lnT_kernel<<<dim3(128,32),dim3(256),0,stream>>>(kv, vT, llng, llnb, l*64, flag);
    transposeB_kernel<<<dim3(8,2,32),tb,0,stream>>>(gv, gvT, 16384LL,0,1, 16384LL, 64, 256);
    // fused attention -> ob   (32-row tiles: grid 128 x 32)
    { AttnP ap; ap.q=qb; ap.k=kv; ap.gk=gk; ap.vT=vT; ap.gvT=gvT; ap.o=ob;
      attn_kernel<<<dim3(128,32),256,0,stream>>>(ap); }
    // h += o@Wo + bo
    { Gemm128P p = mk128(ob, sWoT, h, bo,l*512,flag, 512,512,512,512, 1.f, FLAG_ACC|FLAG_CF32);
      gemm2ph_kernel<128><<<dim3(128,2),512,0,stream>>>(p); }
    // FFN
    ln512_kernel<<<dim3(16384),dim3(256),0,stream>>>(h, ln2g, ln2b, l*512, y, flag);
    { Gemm128P p = mk128(y, sW1T, big, b1,l*2048,flag, 512,512,512,2048, 1.f, FLAG_GELU);
      gemm2ph_kernel<256><<<dim3(64,8),512,0,stream>>>(p); }
    { Gemm128P p = mk128(big, sW2T, h, b2,l*512,flag, 2048,2048,2048,512, 1.f, FLAG_ACC|FLAG_CF32);
      gemm2ph_kernel<128><<<dim3(128,2),512,0,stream>>>(p); }
  }
  // logits = LN_f(h)@Wlog + blog (fp32 out)
  ln512_kernel<<<dim3(16384),dim3(256),0,stream>>>(h, lnfg, lnfb, 0, y, flag);
  cvtT_kernel<<<dim3(16,16,1),tb,0,stream>>>(Wlog, 0, 0, sWqT, 0, 512, 512, flag);
  { Gemm128P p = mk128(y, sWqT, bigf, blog,0,flag, 512,512,512,512, 1.f, FLAG_CF32);
    gemm2ph_kernel<128><<<dim3(128,2),512,0,stream>>>(p); }
  // final head
  zero40_kernel<<<dim3(1),dim3(64),0,stream>>>(part);
  head_kernel<<<dim3(1024),dim3(256),0,stream>>>(bigf, Wfin, part, flag);
  fin_kernel<<<dim3(1),dim3(64),0,stream>>>(part, bfin, d_out, flag);
}

// Round 7
// 2160.513 us; speedup vs baseline: 1.0698x; 1.0142x over previous
//
#include <hip/hip_runtime.h>
#include <hip/hip_bf16.h>

typedef unsigned short u16;
typedef __attribute__((ext_vector_type(8))) short short8;
typedef __attribute__((ext_vector_type(4))) float floatx4;

#define FLAG_GELU   1
#define FLAG_ACC    2
#define FLAG_NN     4
#define FLAG_CF32   8
#define FLAG_ATOMIC 16

__device__ __forceinline__ float bf2f(u16 u){
  union { unsigned u; float f; } c; c.u = ((unsigned)u)<<16; return c.f;
}
__device__ __forceinline__ u16 f2bf(float f){
  union { float f; unsigned u; } c; c.f = f;
  unsigned r = (c.u + 0x7fffu + ((c.u>>16)&1u))>>16;
  return (u16)r;
}
__device__ __forceinline__ float rdin(const void* base, long long idx, int flagv){
  return flagv ? ((const float*)base)[idx] : bf2f(((const u16*)base)[idx]);
}
// tanh-approx GELU via fast exp: tanh(u) = 1 - 2/(e^{2u}+1); saturates correctly.
__device__ __forceinline__ float fast_gelu(float x){
  float u = 0.7978845608028654f*(x + 0.044715f*x*x*x);
  float e = __expf(2.f*u);
  float t = 1.f - 2.f/(e+1.f);
  return 0.5f*x*(1.f+t);
}

// ---------------- input dtype probe ----------------
__global__ void detect_kernel(const void* tok, int* flag){
  __shared__ int cnt;
  if(threadIdx.x==0) cnt=0;
  __syncthreads();
  float v = fabsf(bf2f(((const u16*)tok)[threadIdx.x]));
  int bad = (v < 1e3f) ? 0 : 1;
  atomicAdd(&cnt, bad);
  __syncthreads();
  if(threadIdx.x==0) *flag = (cnt>0) ? 1 : 0;
}

// ---------------- fused dual-dtype convert (+scale) + transpose: src[K][N] -> dst[N][K] bf16 ----------------
__global__ void cvtT_kernel(const void* src, long long off0, long long zstride, u16* __restrict__ dst,
    long long dzstride, int K, int N, float scale, const int* flag){
  __shared__ float tl[32][33];
  int fl = *flag;
  int k0 = blockIdx.x*32, n0 = blockIdx.y*32;
  long long base = off0 + (long long)blockIdx.z*zstride;
  for(int i=threadIdx.y;i<32;i+=8){
    long long idx = base + (long long)(k0+i)*N + n0 + threadIdx.x;
    tl[i][threadIdx.x] = fl ? ((const float*)src)[idx] : bf2f(((const u16*)src)[idx]);
  }
  __syncthreads();
  u16* dz = dst + (long long)blockIdx.z*dzstride;
  for(int i=threadIdx.y;i<32;i+=8)
    dz[(long long)(n0+i)*K + k0 + threadIdx.x] = f2bf(tl[threadIdx.x][i]*scale);
}

// ---------------- bf16 ws->ws transpose, batched ----------------
__global__ void transposeB_kernel(const u16* __restrict__ in, u16* __restrict__ out,
    long long izs0, long long izs1, int zd, long long ozstride, int ldin, int ldout){
  __shared__ u16 tl[32][33];
  int z = blockIdx.z; int z0 = z/zd, z1 = z - z0*zd;
  const u16* ip = in + z0*izs0 + z1*izs1;
  u16* op = out + (long long)z*ozstride;
  int r0 = blockIdx.x*32, c0 = blockIdx.y*32;
  for(int i=threadIdx.y;i<32;i+=8)
    tl[i][threadIdx.x] = ip[(long long)(r0+i)*ldin + c0 + threadIdx.x];
  __syncthreads();
  for(int i=threadIdx.y;i<32;i+=8)
    op[(long long)(c0+i)*ldout + r0 + threadIdx.x] = tl[threadIdx.x][i];
}

// ---------------- fused LN(64) + transpose for local v: qkv -> vT ----------------
// v row (b,h,n) = qkv[b*6291456 + n*1536 + 1024 + h*64 .. +64]; out vT[bh][64][4096].
__global__ __launch_bounds__(256) void lnT_kernel(const u16* __restrict__ qkv, u16* __restrict__ vT,
    const void* g, const void* b_, int goff, const int* flag){
  __shared__ u16 tl[32][72];
  int flagv = *flag;
  int nt = blockIdx.x;          // 0..127 n-tile
  int bh = blockIdx.y;          // 0..31
  int bb = bh>>3, hh = bh&7;
  int t = threadIdx.x;
  int r = t>>3, seg = t&7;
  const u16* src = qkv + (long long)bb*6291456 + (long long)(nt*32 + r)*1536 + 1024 + hh*64 + seg*8;
  u16 buf[8]; *(uint4*)buf = *(const uint4*)src;
  float x[8]; float s=0.f, sq=0.f;
  #pragma unroll
  for(int j=0;j<8;j++){ x[j]=bf2f(buf[j]); s+=x[j]; sq+=x[j]*x[j]; }
  s  += __shfl_xor(s,1);  s  += __shfl_xor(s,2);  s  += __shfl_xor(s,4);
  sq += __shfl_xor(sq,1); sq += __shfl_xor(sq,2); sq += __shfl_xor(sq,4);
  float mu = s*(1.f/64.f), var = sq*(1.f/64.f)-mu*mu;
  float inv = rsqrtf(var+1e-5f);
  #pragma unroll
  for(int j=0;j<8;j++){
    int d = seg*8+j;
    tl[r][d] = f2bf((x[j]-mu)*inv*rdin(g,goff+d,flagv) + rdin(b_,goff+d,flagv));
  }
  __syncthreads();
  int d = t>>2, nc = (t&3)*8;
  u16 ob[8];
  #pragma unroll
  for(int j=0;j<8;j++) ob[j] = tl[nc+j][d];
  *(uint4*)(vT + (long long)bh*262144 + (long long)d*4096 + nt*32 + nc) = *(uint4*)ob;
}

__global__ __launch_bounds__(256) void zerof_kernel(float* p, int n){
  int i = blockIdx.x*256 + threadIdx.x;
  if(i<n) p[i]=0.f;
}

// ---------------- 64x64 batched GEMM (attention pre-stage shapes) ----------------
struct GemmP {
  const u16* A; const u16* B; float* Cf; u16* Ch;
  const void* bias; int biasOff; const int* dflag;
  int K, lda, ldb, ldc;
  long long sA0,sA1,sA2,sB0,sB1,sB2,sC0,sC1,sC2;
  int d0,d1; float alpha; int flags; int ksplit;
};

__global__ __launch_bounds__(256) void gemm_kernel(GemmP p){
  __shared__ __align__(16) u16 As[64][40];
  __shared__ __align__(16) u16 Bs[64][40];
  int z = blockIdx.z;
  int i0 = z / p.d0; int rem = z - i0*p.d0; int i1 = rem / p.d1; int i2 = rem - i1*p.d1;
  const u16* A  = p.A + i0*p.sA0 + i1*p.sA1 + i2*p.sA2;
  const u16* Bp = p.B + i0*p.sB0 + i1*p.sB1 + i2*p.sB2;
  long long cb = i0*p.sC0 + i1*p.sC1 + i2*p.sC2;
  int kbeg = 0, kend = p.K;
  if(p.ksplit){ kbeg = i2*p.ksplit; kend = kbeg + p.ksplit; }
  int m0 = blockIdx.x*64, n0 = blockIdx.y*64;
  int t = threadIdx.x, lane = t&63, wave = t>>6;
  int wm = (wave>>1)*32, wn = (wave&1)*32;
  int quad = lane>>4, l16 = lane&15;
  floatx4 zero4 = {0.f,0.f,0.f,0.f};
  floatx4 acc00=zero4, acc01=zero4, acc10=zero4, acc11=zero4;
  int sr = t>>2, sc = (t&3)*8;
  int bkr = t>>3, bnc = (t&7)*8;
  bool nn = (p.flags & FLAG_NN);
  for(int k0=kbeg;k0<kend;k0+=32){
    uint4 av = *(const uint4*)(A + (long long)(m0+sr)*p.lda + (k0+sc));
    uint4 bv;
    if(nn) bv = *(const uint4*)(Bp + (long long)(k0+bkr)*p.ldb + (n0+bnc));
    else   bv = *(const uint4*)(Bp + (long long)(n0+sr)*p.ldb + (k0+sc));
    *(uint4*)&As[sr][sc] = av;
    if(nn){
      u16 tmp[8]; *(uint4*)tmp = bv;
      #pragma unroll
      for(int j=0;j<8;j++) Bs[bnc+j][bkr] = tmp[j];
    } else {
      *(uint4*)&Bs[sr][sc] = bv;
    }
    __syncthreads();
    short8 a0 = *(const short8*)&As[wm+l16][quad*8];
    short8 a1 = *(const short8*)&As[wm+16+l16][quad*8];
    short8 b0 = *(const short8*)&Bs[wn+l16][quad*8];
    short8 b1 = *(const short8*)&Bs[wn+16+l16][quad*8];
    acc00 = __builtin_amdgcn_mfma_f32_16x16x32_bf16(a0,b0,acc00,0,0,0);
    acc01 = __builtin_amdgcn_mfma_f32_16x16x32_bf16(a0,b1,acc01,0,0,0);
    acc10 = __builtin_amdgcn_mfma_f32_16x16x32_bf16(a1,b0,acc10,0,0,0);
    acc11 = __builtin_amdgcn_mfma_f32_16x16x32_bf16(a1,b1,acc11,0,0,0);
    __syncthreads();
  }
  int flagv = p.bias ? *p.dflag : 0;
  #pragma unroll
  for(int mi=0;mi<2;mi++){
    #pragma unroll
    for(int ni=0;ni<2;ni++){
      floatx4 a = (mi==0)?((ni==0)?acc00:acc01):((ni==0)?acc10:acc11);
      int cg = n0 + wn + ni*16 + l16;
      float bv_ = p.bias ? rdin(p.bias, (long long)p.biasOff + cg, flagv) : 0.f;
      #pragma unroll
      for(int e=0;e<4;e++){
        int rg = m0 + wm + mi*16 + quad*4 + e;
        float v = a[e]*p.alpha + bv_;
        if(p.flags & FLAG_GELU) v = fast_gelu(v);
        long long ci = cb + (long long)rg*p.ldc + cg;
        if(p.flags & FLAG_ATOMIC){
          atomicAdd(&p.Cf[ci], v);
        } else if(p.flags & FLAG_CF32){
          float o2 = v; if(p.flags&FLAG_ACC) o2 += p.Cf[ci];
          p.Cf[ci] = o2;
        } else {
          float o2 = v; if(p.flags&FLAG_ACC) o2 += bf2f(p.Ch[ci]);
          p.Ch[ci] = f2bf(o2);
        }
      }
    }
  }
}

// ---------------- big-GEMM params (shared by 2-phase kernels) ----------------
struct Gemm128P {
  const u16* A; const u16* B; float* Cf; u16* Ch;
  const void* bias; int biasOff; const int* dflag;
  int K, lda, ldb, ldc; float alpha; int flags;
};

// ---------------- BM x 256 GEMM, BK=64, double-buffered 2-phase schedule ----------------
// 512 threads = 8 waves (2M x 4N). Per wave: (BM/2) x 64 output.
// T2 swizzle (rule #21): LDS dest linear; global SOURCE column XOR-permuted
// within each 128B row; ds_read applies the same XOR -> conflict-free (r3: 9.4M->0).
// T1 XCD swizzle REVERTED (r5: wrong dispatch-order model -> 2.7x over-fetch).
template<int BM>
__global__ __launch_bounds__(512) void gemm2ph_kernel(Gemm128P p){
  constexpr int NA   = BM/64;             // A-stage gload_lds instrs per K-tile
  constexpr int HH   = BM/2;              // per-wave M rows
  constexpr int MI   = HH/16;             // M fragments per wave
  constexpr int ABUF = BM*64;             // u16 per A buffer
  constexpr int LDSZ = (BM==256) ? 69632 : 49152;  // max(dbuf, epilogue) u16
  __shared__ __align__(16) u16 lds[LDSZ];
  u16* As = lds;                          // 2 bufs x ABUF
  u16* Bs = lds + 2*ABUF;                 // 2 bufs x 16384
  int m0 = blockIdx.x*BM, n0 = blockIdx.y*256;
  int t = threadIdx.x, lane = t&63, wave = t>>6;
  int quad = lane>>4, l16 = lane&15;
  int wr = wave>>2, wc = wave&3;
  int rowA = t>>3;
  int colk = (((t&7) ^ (rowA&7)))*8;      // inverse-swizzled source column
  const u16* Asrc[NA];
  const u16* Bsrc[4];
  #pragma unroll
  for(int q=0;q<NA;q++) Asrc[q] = p.A + (long long)(m0 + q*64 + rowA)*p.lda + colk;
  #pragma unroll
  for(int q=0;q<4;q++)  Bsrc[q] = p.B + (long long)(n0 + q*64 + rowA)*p.ldb + colk;
  int nk = p.K >> 6;
  floatx4 acc[MI][4] = {};

  auto stage = [&](int buf, int k0){
    #pragma unroll
    for(int q=0;q<NA;q++)
      __builtin_amdgcn_global_load_lds(
        (const __attribute__((address_space(1))) unsigned int*)(Asrc[q] + k0),
        (__attribute__((address_space(3))) unsigned int*)(As + buf*ABUF + q*4096 + wave*512),
        16, 0, 0);
    #pragma unroll
    for(int q=0;q<4;q++)
      __builtin_amdgcn_global_load_lds(
        (const __attribute__((address_space(1))) unsigned int*)(Bsrc[q] + k0),
        (__attribute__((address_space(3))) unsigned int*)(Bs + buf*16384 + q*4096 + wave*512),
        16, 0, 0);
  };

  stage(0, 0);
  __syncthreads();                        // prologue drain: buf0 resident
  int sw = l16&7;                         // read-side XOR (row&7 == l16&7 here)
  for(int kt=0; kt<nk; ++kt){
    int cur = kt&1;
    if(kt+1 < nk) stage(cur^1, (kt+1)*64);  // issue next-tile loads FIRST
    const u16* Ab = As + cur*ABUF;
    const u16* Bb = Bs + cur*16384;
    #pragma unroll
    for(int ks=0; ks<2; ks++){
      short8 a[MI], b[4];
      #pragma unroll
      for(int i=0;i<MI;i++)
        a[i] = *(const short8*)&Ab[(wr*HH + i*16 + l16)*64 + ((((ks<<2)|quad) ^ sw)<<3)];
      #pragma unroll
      for(int j=0;j<4;j++)
        b[j] = *(const short8*)&Bb[(wc*64 + j*16 + l16)*64 + ((((ks<<2)|quad) ^ sw)<<3)];
      #pragma unroll
      for(int i=0;i<MI;i++)
        #pragma unroll
        for(int j=0;j<4;j++)
          acc[i][j] = __builtin_amdgcn_mfma_f32_16x16x32_bf16(a[i], b[j], acc[i][j],0,0,0);
    }
    __syncthreads();                      // reads done by all waves + next buf landed
  }

  int flagv = p.bias ? *p.dflag : 0;
  if(!(p.flags & FLAG_CF32)){
    // bf16 out: transpose tile through LDS (wave-private), store 16B lines.
    u16* Ct = lds + wave*(HH*68);
    #pragma unroll
    for(int j=0;j<4;j++){
      int cg = n0 + wc*64 + j*16 + l16;
      float bv_ = p.bias ? rdin(p.bias, (long long)p.biasOff + cg, flagv) : 0.f;
      #pragma unroll
      for(int i=0;i<MI;i++){
        #pragma unroll
        for(int e=0;e<4;e++){
          float v = acc[i][j][e]*p.alpha + bv_;
          if(p.flags & FLAG_GELU) v = fast_gelu(v);
          Ct[(i*16 + quad*4 + e)*68 + j*16 + l16] = f2bf(v);
        }
      }
    }
    int rsub = lane>>3, csub = (lane&7)*8;
    #pragma unroll
    for(int rr=0; rr<HH/8; rr++){
      int row = rr*8 + rsub;
      uint4 v = *(const uint4*)&Ct[row*68 + csub];
      *(uint4*)(p.Ch + (long long)(m0 + wr*HH + row)*p.ldc + (n0 + wc*64 + csub)) = v;
    }
  } else {
    #pragma unroll
    for(int j=0;j<4;j++){
      int cg = n0 + wc*64 + j*16 + l16;
      float bv_ = p.bias ? rdin(p.bias, (long long)p.biasOff + cg, flagv) : 0.f;
      #pragma unroll
      for(int i=0;i<MI;i++){
        #pragma unroll
        for(int e=0;e<4;e++){
          int rg = m0 + wr*HH + i*16 + quad*4 + e;
          float v = acc[i][j][e]*p.alpha + bv_;
          if(p.flags & FLAG_GELU) v = fast_gelu(v);
          long long ci = (long long)rg*p.ldc + cg;
          float o2 = v; if(p.flags&FLAG_ACC) o2 += p.Cf[ci];
          p.Cf[ci] = o2;
        }
      }
    }
  }
}

// ---------------- fused window attention (occupancy-optimized) ----------------
// q/k live in the merged qkv buffer, row stride 1536 (q at +0 pre-scaled, k at +512 LN'd).
struct AttnP {
  const u16* q;    // qkv base [B][4096][1536]
  const u16* k;    // qkv+512
  const u16* gk;   // [bh][256][64] (LN'd)
  const u16* vT;   // [bh][64][4096] (LN'd local v, transposed)
  const u16* gvT;  // [bh][64][256]  (LN'd global v, transposed)
  u16* o;          // [B][4096][512]
};

__global__ __launch_bounds__(256) void attn_kernel(AttnP p){
  __shared__ __align__(16) u16 S[32*392];   // 32 rows x 392 stride
  __shared__ float ssum[32];
  const int SST = 392;
  int qb = blockIdx.x;          // 0..127 : 32-row q tile
  int bh = blockIdx.y;
  int b = bh>>3, hh = bh&7;
  int w = qb>>2;                // 128-row window this tile belongs to
  int t = threadIdx.x, lane = t&63, wave = t>>6;
  int quad = lane>>4, l16 = lane&15;
  int mbase = qb*32;
  short8 aq[2][2];
  #pragma unroll
  for(int mt=0;mt<2;mt++)
    #pragma unroll
    for(int kc=0;kc<2;kc++)
      aq[mt][kc] = *(const short8*)(p.q + ((long long)b*4096 + mbase + mt*16 + l16)*1536 + hh*64 + kc*32 + quad*8);
  #pragma unroll
  for(int i=0;i<6;i++){
    int ct = wave*6 + i;
    short8 bf0, bf1;
    if(ct<8){
      const u16* kr = p.k + ((long long)b*4096 + w*128 + ct*16 + l16)*1536 + hh*64;
      bf0 = *(const short8*)(kr + quad*8);
      bf1 = *(const short8*)(kr + 32 + quad*8);
    } else {
      const u16* gr = p.gk + ((long long)bh*256 + (ct-8)*16 + l16)*64;
      bf0 = *(const short8*)(gr + quad*8);
      bf1 = *(const short8*)(gr + 32 + quad*8);
    }
    #pragma unroll
    for(int mt=0;mt<2;mt++){
      floatx4 acc = {0.f,0.f,0.f,0.f};
      acc = __builtin_amdgcn_mfma_f32_16x16x32_bf16(aq[mt][0], bf0, acc,0,0,0);
      acc = __builtin_amdgcn_mfma_f32_16x16x32_bf16(aq[mt][1], bf1, acc,0,0,0);
      #pragma unroll
      for(int e=0;e<4;e++)
        S[(mt*16 + quad*4 + e)*SST + ct*16 + l16] = f2bf(acc[e]);
    }
  }
  __syncthreads();
  {
    int r = t>>3, seg = t&7;
    u16* Srow = S + r*SST + seg*48;
    u16 buf[48];
    #pragma unroll
    for(int it=0; it<6; it++)
      *(uint4*)(buf + it*8) = *(const uint4*)(Srow + it*8);
    float mmax = -3.4e38f;
    #pragma unroll
    for(int j=0;j<48;j++) mmax = fmaxf(mmax, bf2f(buf[j]));
    mmax = fmaxf(mmax, __shfl_xor(mmax, 1));
    mmax = fmaxf(mmax, __shfl_xor(mmax, 2));
    mmax = fmaxf(mmax, __shfl_xor(mmax, 4));
    float s = 0.f;
    #pragma unroll
    for(int j=0;j<48;j++){ float e_ = __expf(bf2f(buf[j]) - mmax); s += e_; buf[j] = f2bf(e_); }
    #pragma unroll
    for(int it=0; it<6; it++)
      *(uint4*)(Srow + it*8) = *(const uint4*)(buf + it*8);
    s += __shfl_xor(s, 1);
    s += __shfl_xor(s, 2);
    s += __shfl_xor(s, 4);
    if(seg==0) ssum[r] = 1.f/s;
  }
  __syncthreads();
  int dt = wave;
  floatx4 oacc[2] = {};
  for(int kc=0; kc<12; kc++){
    short8 ap0 = *(const short8*)(S + (l16)*SST + kc*32 + quad*8);
    short8 ap1 = *(const short8*)(S + (16 + l16)*SST + kc*32 + quad*8);
    short8 bv;
    if(kc<4)
      bv = *(const short8*)(p.vT + (long long)bh*262144 + (dt*16+l16)*4096 + w*128 + kc*32 + quad*8);
    else
      bv = *(const short8*)(p.gvT + (long long)bh*16384 + (dt*16+l16)*256 + (kc-4)*32 + quad*8);
    oacc[0] = __builtin_amdgcn_mfma_f32_16x16x32_bf16(ap0, bv, oacc[0],0,0,0);
    oacc[1] = __builtin_amdgcn_mfma_f32_16x16x32_bf16(ap1, bv, oacc[1],0,0,0);
  }
  #pragma unroll
  for(int mt=0;mt<2;mt++){
    #pragma unroll
    for(int e=0;e<4;e++){
      int row = mt*16 + quad*4 + e;
      float inv = ssum[row];
      p.o[((long long)b*4096 + mbase + row)*512 + hh*64 + dt*16 + l16] = f2bf(oacc[mt][e]*inv);
    }
  }
}

// ---------------- embed ----------------
__global__ __launch_bounds__(256) void embed_kernel(const int* __restrict__ x, const void* tok,
    const void* pos, float* __restrict__ h, const int* flag){
  int i = blockIdx.x*256 + threadIdx.x;
  int flagv = *flag;
  int d = i & 511;
  int n = (i>>9) & 4095;
  int bn = i>>9;
  int tid2 = x[bn];
  h[i] = rdin(tok, (long long)tid2*512 + d, flagv) + rdin(pos, (long long)n*512 + d, flagv);
}

// ---------------- LN over 512 (fp32 in, bf16 out) ----------------
__global__ __launch_bounds__(256) void ln512_kernel(const float* __restrict__ h,
    const void* g, const void* b, int goff, u16* __restrict__ y, const int* flag){
  int row = blockIdx.x;
  int flagv = *flag;
  const float* hr = h + (size_t)row*512;
  int t = threadIdx.x;
  float x0 = hr[t], x1 = hr[t+256];
  float s1 = x0+x1, s2 = x0*x0+x1*x1;
  for(int o=32;o>0;o>>=1){ s1 += __shfl_down(s1,o,64); s2 += __shfl_down(s2,o,64); }
  __shared__ float sh1[4], sh2[4];
  int wv=t>>6, ln=t&63;
  if(ln==0){ sh1[wv]=s1; sh2[wv]=s2; }
  __syncthreads();
  float st = sh1[0]+sh1[1]+sh1[2]+sh1[3];
  float qt = sh2[0]+sh2[1]+sh2[2]+sh2[3];
  float mu = st*(1.f/512.f);
  float var = qt*(1.f/512.f) - mu*mu;
  float inv = rsqrtf(var+1e-5f);
  u16* yr = y + (size_t)row*512;
  yr[t]     = f2bf((x0-mu)*inv*rdin(g,goff+t,flagv)     + rdin(b,goff+t,flagv));
  yr[t+256] = f2bf((x1-mu)*inv*rdin(g,goff+t+256,flagv) + rdin(b,goff+t+256,flagv));
}

// ---------------- LN over 64; optional fp32 input; strided ----------------
__global__ __launch_bounds__(256) void ln64_kernel(const u16* __restrict__ in, const float* __restrict__ inF,
    u16* __restrict__ out, const void* g, const void* b, int goff,
    long long s0, long long s1v, long long s2v, int d0, int d1, const int* flag){
  int r = blockIdx.x*4 + (threadIdx.x>>6);
  int ln = threadIdx.x&63;
  int flagv = *flag;
  int i0 = r/d0; int rem = r - i0*d0; int i1 = rem/d1; int i2 = rem - i1*d1;
  long long off = i0*s0 + i1*s1v + i2*s2v;
  float x = inF ? inF[off+ln] : bf2f(in[off + ln]);
  float s = x, sq = x*x;
  for(int o=32;o>0;o>>=1){ s += __shfl_down(s,o,64); sq += __shfl_down(sq,o,64); }
  s = __shfl(s,0,64); sq = __shfl(sq,0,64);
  float mu = s*(1.f/64.f), var = sq*(1.f/64.f)-mu*mu;
  float inv = rsqrtf(var+1e-5f);
  out[off + ln] = f2bf((x-mu)*inv*rdin(g,goff+ln,flagv) + rdin(b,goff+ln,flagv));
}

// ---------------- softmax over 4096 (bf16, in place) ----------------
__global__ __launch_bounds__(256) void softmax4096_kernel(u16* __restrict__ p){
  u16* pr = p + (size_t)blockIdx.x*4096;
  int t = threadIdx.x;
  u16 tmp[16];
  *(uint4*)tmp     = *(const uint4*)(pr + t*16);
  *(uint4*)(tmp+8) = *(const uint4*)(pr + t*16 + 8);
  float xs[16]; float m=-3.4e38f;
  #pragma unroll
  for(int i=0;i<16;i++){ xs[i]=bf2f(tmp[i]); m=fmaxf(m,xs[i]); }
  for(int o=32;o>0;o>>=1) m = fmaxf(m, __shfl_down(m,o,64));
  __shared__ float sm[4]; __shared__ float sv[4];
  int wv=t>>6, ln=t&63;
  if(ln==0) sm[wv]=m;
  __syncthreads();
  m = fmaxf(fmaxf(sm[0],sm[1]),fmaxf(sm[2],sm[3]));
  float s=0;
  #pragma unroll
  for(int i=0;i<16;i++){ xs[i]=__expf(xs[i]-m); s+=xs[i]; }
  for(int o=32;o>0;o>>=1) s += __shfl_down(s,o,64);
  if(ln==0) sv[wv]=s;
  __syncthreads();
  s = sv[0]+sv[1]+sv[2]+sv[3];
  float inv = 1.f/s;
  #pragma unroll
  for(int i=0;i<16;i++) tmp[i]=f2bf(xs[i]*inv);
  *(uint4*)(pr + t*16)     = *(uint4*)tmp;
  *(uint4*)(pr + t*16 + 8) = *(uint4*)(tmp+8);
}

// ---------------- head ----------------
__global__ void zero40_kernel(float* p){ if(threadIdx.x<40) p[threadIdx.x]=0.f; }

// out[b][c] = sum_j logits[b][j] * W[j][c].  Grid = 1024 blocks, each owns 2048
// CONSECUTIVE W rows and all 4 batches (W read exactly once, coalesced).
__global__ __launch_bounds__(256) void head_kernel(const float* __restrict__ logits,
    const void* wfin, float* __restrict__ part, const int* flag){
  __shared__ __align__(16) u16 Wl[20480];   // 2048 rows x 10 bf16
  __shared__ float redl[4][40];
  int flagv = *flag;
  int t = threadIdx.x;
  long long rbase = (long long)blockIdx.x*2048;
  float acc[4][10];
  #pragma unroll
  for(int b4=0;b4<4;b4++)
    #pragma unroll
    for(int c=0;c<10;c++) acc[b4][c]=0.f;

  if(!flagv){
    const uint4* src = (const uint4*)((const u16*)wfin + rbase*10);
    uint4* dst = (uint4*)Wl;
    #pragma unroll
    for(int i=0;i<10;i++) dst[t + i*256] = src[t + i*256];
    __syncthreads();
    const unsigned* Wd = (const unsigned*)Wl;
    #pragma unroll
    for(int i=0;i<8;i++){
      int r = t + i*256;
      float l0 = logits[rbase + r];
      float l1 = logits[2097152 + rbase + r];
      float l2 = logits[4194304 + rbase + r];
      float l3 = logits[6291456 + rbase + r];
      #pragma unroll
      for(int k2=0;k2<5;k2++){
        unsigned d = Wd[r*5 + k2];
        float w0 = bf2f((u16)(d & 0xffffu));
        float w1 = bf2f((u16)(d >> 16));
        acc[0][2*k2]   += l0*w0; acc[0][2*k2+1] += l0*w1;
        acc[1][2*k2]   += l1*w0; acc[1][2*k2+1] += l1*w1;
        acc[2][2*k2]   += l2*w0; acc[2][2*k2+1] += l2*w1;
        acc[3][2*k2]   += l3*w0; acc[3][2*k2+1] += l3*w1;
      }
    }
  } else {
    #pragma unroll
    for(int i=0;i<8;i++){
      int r = t + i*256;
      float l0 = logits[rbase + r];
      float l1 = logits[2097152 + rbase + r];
      float l2 = logits[4194304 + rbase + r];
      float l3 = logits[6291456 + rbase + r];
      const float* wr = (const float*)wfin + (rbase + r)*10;
      #pragma unroll
      for(int c=0;c<10;c++){
        float w = wr[c];
        acc[0][c] += l0*w; acc[1][c] += l1*w; acc[2][c] += l2*w; acc[3][c] += l3*w;
      }
    }
  }
  int wv = t>>6, ln = t&63;
  #pragma unroll
  for(int b4=0;b4<4;b4++)
    #pragma unroll
    for(int c=0;c<10;c++){
      float v = acc[b4][c];
      for(int o=32;o>0;o>>=1) v += __shfl_down(v,o,64);
      if(ln==0) redl[wv][b4*10+c] = v;
    }
  __syncthreads();
  if(t<40) atomicAdd(&part[t], redl[0][t]+redl[1][t]+redl[2][t]+redl[3][t]);
}

__global__ void fin_kernel(const float* __restrict__ part, const void* bfin, void* out, const int* flag){
  int i=threadIdx.x;
  int flagv = *flag;
  if(i<40){
    float r = part[i] + rdin(bfin, i%10, flagv);
    if(flagv) ((float*)out)[i] = r;
    else      ((u16*)out)[i]   = f2bf(r);
  }
}

// ---------------- workspace layout (bytes) — total ~209.8 MB ----------------
static const size_t OFF_H    = 0;
static const size_t OFF_Y    = 33554432;
static const size_t OFF_GKF  = 33554432;
static const size_t OFF_GVF  = 35651584;
static const size_t OFF_QKV  = 50331648;    // [4][4096][1536] bf16 = 48 MB (q|k|v merged)
static const size_t OFF_GK   = 100663296;
static const size_t OFF_GV   = 101711872;
static const size_t OFF_BIG  = 102760448;
static const size_t OFF_KT   = 169869312;   // gvT
static const size_t OFF_VT   = 186646528;   // LN'd v^T
static const size_t OFF_WTP  = 203423744;
static const size_t OFF_WQKV = 203554816;   // [1536][512] bf16 = 1.5 MB (Wq*0.125 | Wkv)^T
static const size_t OFF_WOT  = 205127680;
static const size_t OFF_W1T  = 205651968;
static const size_t OFF_W2T  = 207749120;
static const size_t OFF_PART = 209846272;
static const size_t OFF_FLAG = 209846528;
static const size_t WS_NEED  = 209846784;

static inline GemmP mkg(const void*A,const void*B,void*C,const void*bias,int biasOff,const int* dflag,
  int K,int lda,int ldb,int ldc,
  long long a0,long long a1,long long a2,long long b0,long long b1,long long b2,
  long long c0,long long c1,long long c2,int d0,int d1,float alpha,int flags,int ksplit){
  GemmP p; p.A=(const u16*)A; p.B=(const u16*)B;
  p.Cf=(float*)C; p.Ch=(u16*)C; p.bias=bias; p.biasOff=biasOff; p.dflag=dflag;
  p.K=K;p.lda=lda;p.ldb=ldb;p.ldc=ldc;
  p.sA0=a0;p.sA1=a1;p.sA2=a2;p.sB0=b0;p.sB1=b1;p.sB2=b2;p.sC0=c0;p.sC1=c1;p.sC2=c2;
  p.d0=d0;p.d1=d1;p.alpha=alpha;p.flags=flags;p.ksplit=ksplit; return p;
}
static inline Gemm128P mk128(const void*A,const void*B,void*C,const void*bias,int biasOff,const int* dflag,
  int K,int lda,int ldb,int ldc,float alpha,int flags){
  Gemm128P p; p.A=(const u16*)A; p.B=(const u16*)B;
  p.Cf=(float*)C; p.Ch=(u16*)C; p.bias=bias; p.biasOff=biasOff; p.dflag=dflag;
  p.K=K;p.lda=lda;p.ldb=ldb;p.ldc=ldc;p.alpha=alpha;p.flags=flags; return p;
}

extern "C" void kernel_launch(void* const* d_in, const int* in_sizes, int n_in,
                              void* d_out, int out_size, void* d_ws, size_t ws_size,
                              hipStream_t stream){
  (void)in_sizes;(void)n_in;(void)out_size;
  if(ws_size < WS_NEED) return;
  const int*  x    = (const int*)d_in[0];
  const void* tok  = d_in[1];
  const void* pos  = d_in[2];
  const void* ln1g = d_in[3];
  const void* ln1b = d_in[4];
  const void* Wq   = d_in[5];
  const void* Wkv  = d_in[6];
  const void* Wp   = d_in[7];
  const void* llng = d_in[8];
  const void* llnb = d_in[9];
  const void* glng = d_in[10];
  const void* glnb = d_in[11];
  const void* Wo   = d_in[12];
  const void* bo   = d_in[13];
  const void* ln2g = d_in[14];
  const void* ln2b = d_in[15];
  const void* W1   = d_in[16];
  const void* b1   = d_in[17];
  const void* W2   = d_in[18];
  const void* b2   = d_in[19];
  const void* lnfg = d_in[20];
  const void* lnfb = d_in[21];
  const void* Wlog = d_in[22];
  const void* blog = d_in[23];
  const void* Wfin = d_in[24];
  const void* bfin = d_in[25];

  char* ws = (char*)d_ws;
  float* h    = (float*)(ws + OFF_H);
  u16* y      = (u16*)(ws + OFF_Y);
  u16* ob     = (u16*)(ws + OFF_Y);
  float* gkF  = (float*)(ws + OFF_GKF);
  float* gvF  = (float*)(ws + OFF_GVF);
  u16* qkv    = (u16*)(ws + OFF_QKV);
  u16* gk     = (u16*)(ws + OFF_GK);
  u16* gv     = (u16*)(ws + OFF_GV);
  u16* big    = (u16*)(ws + OFF_BIG);
  float* bigf = (float*)(ws + OFF_BIG);
  u16* gvT    = (u16*)(ws + OFF_KT);
  u16* vT     = (u16*)(ws + OFF_VT);
  u16* wTp    = (u16*)(ws + OFF_WTP);
  u16* sWqkvT = (u16*)(ws + OFF_WQKV);
  u16* sWoT   = (u16*)(ws + OFF_WOT);
  u16* sW1T   = (u16*)(ws + OFF_W1T);
  u16* sW2T   = (u16*)(ws + OFF_W2T);
  float* part = (float*)(ws + OFF_PART);
  int* flag   = (int*)(ws + OFF_FLAG);

  dim3 tb(32,8);
  detect_kernel<<<dim3(1),dim3(256),0,stream>>>(tok, flag);
  cvtT_kernel<<<dim3(2,8,4),tb,0,stream>>>(Wp, 0, 16384, wTp, 16384, 64, 256, 1.f, flag);
  embed_kernel<<<dim3(32768),dim3(256),0,stream>>>(x, tok, pos, h, flag);

  for(int l=0;l<4;l++){
    // merged qkv weight: rows 0-511 = Wq^T * SCALE, rows 512-1535 = Wkv^T
    cvtT_kernel<<<dim3(16,16,1),tb,0,stream>>>(Wq,  (long long)l*262144,  0, sWqkvT, 0, 512, 512,  0.125f, flag);
    cvtT_kernel<<<dim3(16,32,1),tb,0,stream>>>(Wkv, (long long)l*524288,  0, sWqkvT + 262144, 0, 512, 1024, 1.f, flag);
    cvtT_kernel<<<dim3(16,16,1),tb,0,stream>>>(Wo,  (long long)l*262144,  0, sWoT,  0, 512, 512,  1.f, flag);
    cvtT_kernel<<<dim3(16,64,1),tb,0,stream>>>(W1,  (long long)l*1048576, 0, sW1T,  0, 512, 2048, 1.f, flag);
    cvtT_kernel<<<dim3(64,16,1),tb,0,stream>>>(W2,  (long long)l*1048576, 0, sW2T,  0, 2048, 512, 1.f, flag);

    // y = LN1(h)
    ln512_kernel<<<dim3(16384),dim3(256),0,stream>>>(h, ln1g, ln1b, l*512, y, flag);
    // qkv = y @ [Wq*s | Wkv]  (one GEMM, N=1536)
    { Gemm128P p = mk128(y, sWqkvT, qkv, nullptr,0,flag, 512,512,512,1536, 1.f, 0);
      gemm2ph_kernel<256><<<dim3(64,6),512,0,stream>>>(p); }
    zerof_kernel<<<dim3(4096),dim3(256),0,stream>>>(gkF, 1048576);
    // p[bh][r][n] = WpT[r,:]·k[bh,n,:]   (k = qkv+512, stride 1536)
    { GemmP p = mkg(wTp + (size_t)l*16384, qkv+512, big, nullptr,0,flag, 64,64,1536,4096,
        0,0,0, 6291456LL,64,0, 8388608LL,1048576LL,0, 8,1, 1.f, 0, 0);
      gemm_kernel<<<dim3(4,64,32),256,0,stream>>>(p); }
    softmax4096_kernel<<<dim3(8192),dim3(256),0,stream>>>(big);
    // gk/gv = p@k / p@v via split-K=8 + fp32 atomics, B=qkv direct (NN mode).
    { GemmP p = mkg(big, qkv+512, gkF, nullptr,0,flag, 4096,4096,1536,64,
        8388608LL,1048576LL,0, 6291456LL,64,0, 131072LL,16384LL,0, 64,8, 1.f,
        FLAG_CF32|FLAG_ATOMIC|FLAG_NN, 512);
      gemm_kernel<<<dim3(4,1,256),256,0,stream>>>(p); }
    { GemmP p = mkg(big, qkv+1024, gvF, nullptr,0,flag, 4096,4096,1536,64,
        8388608LL,1048576LL,0, 6291456LL,64,0, 131072LL,16384LL,0, 64,8, 1.f,
        FLAG_CF32|FLAG_ATOMIC|FLAG_NN, 512);
      gemm_kernel<<<dim3(4,1,256),256,0,stream>>>(p); }
    // gLN; local k LN in place; local v LN fused into transpose (lnT)
    ln64_kernel<<<dim3(2048),dim3(256),0,stream>>>(gk, gkF, gk, glng, glnb, l*64, 64,1,1, 1,1, flag);
    ln64_kernel<<<dim3(2048),dim3(256),0,stream>>>(gv, gvF, gv, glng, glnb, l*64, 64,1,1, 1,1, flag);
    ln64_kernel<<<dim3(32768),dim3(256),0,stream>>>(qkv+512, nullptr, qkv+512, llng, llnb, l*64, 6291456LL,64,1536, 32768,4096, flag);
    lnT_kernel<<<dim3(128,32),dim3(256),0,stream>>>(qkv, vT, llng, llnb, l*64, flag);
    transposeB_kernel<<<dim3(8,2,32),tb,0,stream>>>(gv, gvT, 16384LL,0,1, 16384LL, 64, 256);
    // fused attention -> ob   (32-row tiles: grid 128 x 32)
    { AttnP ap; ap.q=qkv; ap.k=qkv+512; ap.gk=gk; ap.vT=vT; ap.gvT=gvT; ap.o=ob;
      attn_kernel<<<dim3(128,32),256,0,stream>>>(ap); }
    // h += o@Wo + bo
    { Gemm128P p = mk128(ob, sWoT, h, bo,l*512,flag, 512,512,512,512, 1.f, FLAG_ACC|FLAG_CF32);
      gemm2ph_kernel<128><<<dim3(128,2),512,0,stream>>>(p); }
    // FFN
    ln512_kernel<<<dim3(16384),dim3(256),0,stream>>>(h, ln2g, ln2b, l*512, y, flag);
    { Gemm128P p = mk128(y, sW1T, big, b1,l*2048,flag, 512,512,512,2048, 1.f, FLAG_GELU);
      gemm2ph_kernel<256><<<dim3(64,8),512,0,stream>>>(p); }
    { Gemm128P p = mk128(big, sW2T, h, b2,l*512,flag, 2048,2048,2048,512, 1.f, FLAG_ACC|FLAG_CF32);
      gemm2ph_kernel<128><<<dim3(128,2),512,0,stream>>>(p); }
  }
  // logits = LN_f(h)@Wlog + blog (fp32 out)
  ln512_kernel<<<dim3(16384),dim3(256),0,stream>>>(h, lnfg, lnfb, 0, y, flag);
  cvtT_kernel<<<dim3(16,16,1),tb,0,stream>>>(Wlog, 0, 0, sWqkvT, 0, 512, 512, 1.f, flag);
  { Gemm128P p = mk128(y, sWqkvT, bigf, blog,0,flag, 512,512,512,512, 1.f, FLAG_CF32);
    gemm2ph_kernel<128><<<dim3(128,2),512,0,stream>>>(p); }
  // final head
  zero40_kernel<<<dim3(1),dim3(64),0,stream>>>(part);
  head_kernel<<<dim3(1024),dim3(256),0,stream>>>(bigf, Wfin, part, flag);
  fin_kernel<<<dim3(1),dim3(64),0,stream>>>(part, bfin, d_out, flag);
}